// Round 7
// baseline (397.005 us; speedup 1.0000x reference)
//
#include <hip/hip_runtime.h>
#include <hip/hip_bf16.h>

typedef __attribute__((ext_vector_type(8))) short short8;
typedef __attribute__((ext_vector_type(4))) float floatx4;
typedef unsigned short u16;
typedef unsigned int u32;

#define QSCALE 0.1803368801111244f   // 0.125 * log2(e): folded into Q so softmax is exp2(S)

__device__ __forceinline__ u16 f2b(float f) {
    union { float f; u32 u; } v; v.f = f;
    u32 r = v.u + 0x7fffu + ((v.u >> 16) & 1u);   // RNE
    return (u16)(r >> 16);
}

__device__ __forceinline__ void gload(const u16* g, u16* l) {
    __builtin_amdgcn_global_load_lds((const __attribute__((address_space(1))) void*)g,
                                     (__attribute__((address_space(3))) void*)l, 16, 0, 0);
}

// ---------------- batched weight transpose + fp32->bf16 (16 x 512x512 tiles) ----------------
struct TPent { const float* s; u16* d; int O; int dI; };
struct TP16 { TPent e[16]; };
__global__ __launch_bounds__(256) void transpose_convert16(TP16 p) {
    __shared__ float t[32][33];
    TPent e = p.e[blockIdx.z];
    int o0 = blockIdx.x * 32, i0 = blockIdx.y * 32;
    int tx = threadIdx.x, ty = threadIdx.y;
#pragma unroll
    for (int k = 0; k < 32; k += 8) t[ty + k][tx] = e.s[(size_t)(i0 + ty + k) * e.O + o0 + tx];
    __syncthreads();
#pragma unroll
    for (int k = 0; k < 32; k += 8) e.d[(size_t)(o0 + ty + k) * e.dI + i0 + tx] = f2b(t[tx][ty + k]);
}

// gather 5 bias vectors into 2 concat buffers. grid 10 x 256
__global__ __launch_bounds__(256) void gather_bias(const float* b0, const float* b1, const float* b2,
                                                   const float* b3, const float* b4,
                                                   float* dqkv, float* dkv) {
    int i = blockIdx.x * 256 + threadIdx.x;
    if      (i < 512)  dqkv[i] = b0[i];
    else if (i < 1024) dqkv[i] = b1[i - 512];
    else if (i < 1536) dqkv[i] = b2[i - 1024];
    else if (i < 2048) dkv[i - 1536] = b3[i - 1536];
    else               dkv[i - 1536] = b4[i - 2048];
}

// fp32 -> bf16 for x and enc in one launch. grid 2048 x 256, 4 elems each.
__global__ __launch_bounds__(256) void cvt_bf16_2(const float4* __restrict__ s0, ushort4* __restrict__ d0,
                                                  const float4* __restrict__ s1, ushort4* __restrict__ d1) {
    int i = blockIdx.x * 256 + threadIdx.x;
    float4 v = s0[i];
    ushort4 o; o.x = f2b(v.x); o.y = f2b(v.y); o.z = f2b(v.z); o.w = f2b(v.w);
    d0[i] = o;
    v = s1[i];
    o.x = f2b(v.x); o.y = f2b(v.y); o.z = f2b(v.z); o.w = f2b(v.w);
    d1[i] = o;
}

// ---------------- GEMM 64x128: C = A[M,K] @ Bt[N,K] + epilogue. grid (M/64, N/128) ----------------
__global__ __launch_bounds__(256) void gemm64x128(
    const u16* __restrict__ A, int lda,
    const u16* __restrict__ B, int ldb,
    int K,
    const float* __restrict__ bias,
    const float* __restrict__ residual,
    float* __restrict__ out_f, u16* __restrict__ out_b,
    int out_stride, int scale_ncols, int gelu_flag)
{
    __shared__ u16 lA[64 * 32];
    __shared__ u16 lB[128 * 32];
    int tid = threadIdx.x, wave = tid >> 6, lane = tid & 63;
    int g4 = lane >> 4, c16 = lane & 15;
    int bm = blockIdx.x * 64, bn = blockIdx.y * 128;
    int wm = (wave >> 1) * 32, wn = (wave & 1) * 64;
    int srow = tid >> 2, skseg = (tid & 3) * 8;
    const u16* Ar = A + (size_t)(bm + srow) * lda + skseg;
    const u16* Br = B + (size_t)(bn + srow) * ldb + skseg;
    size_t b64o = (size_t)64 * ldb;

    floatx4 acc[2][4];
#pragma unroll
    for (int i = 0; i < 2; i++)
#pragma unroll
        for (int j = 0; j < 4; j++) acc[i][j] = (floatx4){0.f, 0.f, 0.f, 0.f};

    for (int kt = 0; kt < K; kt += 32) {
        __syncthreads();
        gload(Ar + kt,        lA + wave * 512);
        gload(Br + kt,        lB + wave * 512);
        gload(Br + kt + b64o, lB + 2048 + wave * 512);
        __syncthreads();
        short8 aF[2], bF[4];
#pragma unroll
        for (int i = 0; i < 2; i++) aF[i] = *(const short8*)&lA[(wm + i * 16 + c16) * 32 + g4 * 8];
#pragma unroll
        for (int j = 0; j < 4; j++) bF[j] = *(const short8*)&lB[(wn + j * 16 + c16) * 32 + g4 * 8];
#pragma unroll
        for (int i = 0; i < 2; i++)
#pragma unroll
            for (int j = 0; j < 4; j++)
                acc[i][j] = __builtin_amdgcn_mfma_f32_16x16x32_bf16(aF[i], bF[j], acc[i][j], 0, 0, 0);
    }

#pragma unroll
    for (int i = 0; i < 2; i++) {
        int row0 = bm + wm + i * 16 + g4 * 4;
#pragma unroll
        for (int j = 0; j < 4; j++) {
            int col = bn + wn + j * 16 + c16;
            float bv = bias[col];
#pragma unroll
            for (int r = 0; r < 4; r++) {
                int row = row0 + r;
                float v = acc[i][j][r] + bv;
                if (col < scale_ncols) v *= QSCALE;
                if (gelu_flag) v = 0.5f * v * (1.f + erff(v * 0.70710678118654752f));
                if (residual) v += residual[(size_t)row * out_stride + col];
                if (out_f) out_f[(size_t)row * out_stride + col] = v;
                else       out_b[(size_t)row * out_stride + col] = f2b(v);
            }
        }
    }
}

// ---------------- dual GEMM 64x128 (QKV_m for by<ys, KV_c for by>=ys), bf16 out ----------------
__global__ __launch_bounds__(256) void gemm64x128_dual(
    const u16* __restrict__ A0, const u16* __restrict__ B0, const float* __restrict__ bias0,
    u16* __restrict__ out0, int ostride0, int scale0,
    const u16* __restrict__ A1, const u16* __restrict__ B1, const float* __restrict__ bias1,
    u16* __restrict__ out1, int ostride1,
    int ys, int K, int lda, int ldb)
{
    __shared__ u16 lA[64 * 32];
    __shared__ u16 lB[128 * 32];
    int tid = threadIdx.x, wave = tid >> 6, lane = tid & 63;
    int g4 = lane >> 4, c16 = lane & 15;
    int by = blockIdx.y;
    const u16* A; const u16* B; const float* bias; u16* out; int ostride, scaleN, bn;
    if (by < ys) { A = A0; B = B0; bias = bias0; out = out0; ostride = ostride0; scaleN = scale0; bn = by * 128; }
    else         { A = A1; B = B1; bias = bias1; out = out1; ostride = ostride1; scaleN = 0;      bn = (by - ys) * 128; }
    int bm = blockIdx.x * 64;
    int wm = (wave >> 1) * 32, wn = (wave & 1) * 64;
    int srow = tid >> 2, skseg = (tid & 3) * 8;
    const u16* Ar = A + (size_t)(bm + srow) * lda + skseg;
    const u16* Br = B + (size_t)(bn + srow) * ldb + skseg;
    size_t b64o = (size_t)64 * ldb;

    floatx4 acc[2][4];
#pragma unroll
    for (int i = 0; i < 2; i++)
#pragma unroll
        for (int j = 0; j < 4; j++) acc[i][j] = (floatx4){0.f, 0.f, 0.f, 0.f};

    for (int kt = 0; kt < K; kt += 32) {
        __syncthreads();
        gload(Ar + kt,        lA + wave * 512);
        gload(Br + kt,        lB + wave * 512);
        gload(Br + kt + b64o, lB + 2048 + wave * 512);
        __syncthreads();
        short8 aF[2], bF[4];
#pragma unroll
        for (int i = 0; i < 2; i++) aF[i] = *(const short8*)&lA[(wm + i * 16 + c16) * 32 + g4 * 8];
#pragma unroll
        for (int j = 0; j < 4; j++) bF[j] = *(const short8*)&lB[(wn + j * 16 + c16) * 32 + g4 * 8];
#pragma unroll
        for (int i = 0; i < 2; i++)
#pragma unroll
            for (int j = 0; j < 4; j++)
                acc[i][j] = __builtin_amdgcn_mfma_f32_16x16x32_bf16(aF[i], bF[j], acc[i][j], 0, 0, 0);
    }

#pragma unroll
    for (int i = 0; i < 2; i++) {
        int row0 = bm + wm + i * 16 + g4 * 4;
#pragma unroll
        for (int j = 0; j < 4; j++) {
            int col = bn + wn + j * 16 + c16;
            float bv = bias[col];
#pragma unroll
            for (int r = 0; r < 4; r++) {
                float v = acc[i][j][r] + bv;
                if (col < scaleN) v *= QSCALE;
                out[(size_t)(row0 + r) * ostride + col] = f2b(v);
            }
        }
    }
}

// ---------------- GEMM 64x64, bf16/fp32 out, single-pass (used for Q_c) ----------------
__global__ __launch_bounds__(256) void gemm64x64(
    const u16* __restrict__ A, int lda,
    const u16* __restrict__ B, int ldb,
    int K,
    const float* __restrict__ bias,
    const float* __restrict__ residual,
    float* __restrict__ out_f, u16* __restrict__ out_b,
    int out_stride, int scale_ncols)
{
    __shared__ u16 lA[64 * 32];
    __shared__ u16 lB[64 * 32];
    int tid = threadIdx.x, wave = tid >> 6, lane = tid & 63;
    int g4 = lane >> 4, c16 = lane & 15;
    int bm = blockIdx.x * 64, bn = blockIdx.y * 64;
    int wm = wave * 16;
    int srow = tid >> 2, skseg = (tid & 3) * 8;
    const u16* Ar = A + (size_t)(bm + srow) * lda + skseg;
    const u16* Br = B + (size_t)(bn + srow) * ldb + skseg;

    floatx4 acc[4];
#pragma unroll
    for (int j = 0; j < 4; j++) acc[j] = (floatx4){0.f, 0.f, 0.f, 0.f};

    for (int kt = 0; kt < K; kt += 32) {
        __syncthreads();
        gload(Ar + kt, lA + wave * 512);
        gload(Br + kt, lB + wave * 512);
        __syncthreads();
        short8 aF = *(const short8*)&lA[(wm + c16) * 32 + g4 * 8];
        short8 bF[4];
#pragma unroll
        for (int j = 0; j < 4; j++) bF[j] = *(const short8*)&lB[(j * 16 + c16) * 32 + g4 * 8];
#pragma unroll
        for (int j = 0; j < 4; j++)
            acc[j] = __builtin_amdgcn_mfma_f32_16x16x32_bf16(aF, bF[j], acc[j], 0, 0, 0);
    }

    int row0 = bm + wm + g4 * 4;
#pragma unroll
    for (int j = 0; j < 4; j++) {
        int col = bn + j * 16 + c16;
        float bv = bias[col];
#pragma unroll
        for (int r = 0; r < 4; r++) {
            int row = row0 + r;
            float v = acc[j][r] + bv;
            if (col < scale_ncols) v *= QSCALE;
            if (residual) v += residual[(size_t)row * out_stride + col];
            if (out_f) out_f[(size_t)row * out_stride + col] = v;
            else       out_b[(size_t)row * out_stride + col] = f2b(v);
        }
    }
}

// ---------------- GEMM 64x64 K-split-2: fp32 partials. grid (M/64, N/64, 2) ----------------
__global__ __launch_bounds__(256) void gemm64x64s(
    const u16* __restrict__ A, int lda,
    const u16* __restrict__ B, int ldb,
    int Ksub,
    const float* __restrict__ bias,
    const float* __restrict__ residual,
    float* __restrict__ out0, int out_stride)
{
    __shared__ u16 lA[64 * 32];
    __shared__ u16 lB[64 * 32];
    int tid = threadIdx.x, wave = tid >> 6, lane = tid & 63;
    int g4 = lane >> 4, c16 = lane & 15;
    int bm = blockIdx.x * 64, bn = blockIdx.y * 64, sp = blockIdx.z;
    int wm = wave * 16;
    int srow = tid >> 2, skseg = (tid & 3) * 8 + sp * Ksub;
    const u16* Ar = A + (size_t)(bm + srow) * lda + skseg;
    const u16* Br = B + (size_t)(bn + srow) * ldb + skseg;

    floatx4 acc[4];
#pragma unroll
    for (int j = 0; j < 4; j++) acc[j] = (floatx4){0.f, 0.f, 0.f, 0.f};

    for (int kt = 0; kt < Ksub; kt += 32) {
        __syncthreads();
        gload(Ar + kt, lA + wave * 512);
        gload(Br + kt, lB + wave * 512);
        __syncthreads();
        short8 aF = *(const short8*)&lA[(wm + c16) * 32 + g4 * 8];
        short8 bF[4];
#pragma unroll
        for (int j = 0; j < 4; j++) bF[j] = *(const short8*)&lB[(j * 16 + c16) * 32 + g4 * 8];
#pragma unroll
        for (int j = 0; j < 4; j++)
            acc[j] = __builtin_amdgcn_mfma_f32_16x16x32_bf16(aF, bF[j], acc[j], 0, 0, 0);
    }

    float* out = out0 + (size_t)sp * 4096 * 512;
    int row0 = bm + wm + g4 * 4;
#pragma unroll
    for (int j = 0; j < 4; j++) {
        int col = bn + j * 16 + c16;
        float bv = (sp == 0) ? bias[col] : 0.f;
#pragma unroll
        for (int r = 0; r < 4; r++) {
            int row = row0 + r;
            float v = acc[j][r] + bv;
            if (sp == 0 && residual) v += residual[(size_t)row * out_stride + col];
            out[(size_t)row * out_stride + col] = v;
        }
    }
}

// ---------------- flash attention v6: 16 KB LDS (4 blocks/CU), K direct-from-global ----------
// grid (32 q-tiles, B*H, 4 splits), block 256. Split s: tiles {s, s+4, ...}.
// lVT + lP only, no pads: 16B-chunk XOR swizzle chunk^=(row^row>>3)&7.
// K fragments loaded straight from global (L2-resident), prefetched 1 iter ahead.
__global__ __launch_bounds__(256, 4) void attn_fused(
    const u16* __restrict__ Qp, int q_stride,
    const u16* __restrict__ Kp, int kv_stride,
    const u16* __restrict__ Vp,
    float* __restrict__ Opart,   // [4][16][2048][64]
    float* __restrict__ Lpart,   // [4][16][2048]
    int causal)
{
    __shared__ u16 lVT[64 * 64];     // [dh][key], swizzled
    __shared__ u16 lP[4][16 * 64];   // per-wave [qrow][key], swizzled
    int tid = threadIdx.x, wave = tid >> 6, lane = tid & 63;
    int g4 = lane >> 4, c16 = lane & 15;
    int qt = blockIdx.x, bh = blockIdx.y, sp = blockIdx.z;
    size_t rowbase = (size_t)(bh >> 3) * 2048;
    int hoff = (bh & 7) * 64;
    const u16* Q = Qp + rowbase * q_stride + hoff;
    const u16* K = Kp + rowbase * kv_stride + hoff;
    const u16* V = Vp + rowbase * kv_stride + hoff;

    int qrow0 = qt * 64 + wave * 16;
    short8 qf0 = *(const short8*)&Q[(size_t)(qrow0 + c16) * q_stride + g4 * 8];
    short8 qf1 = *(const short8*)&Q[(size_t)(qrow0 + c16) * q_stride + g4 * 8 + 32];

    // V staging addresses
    int vk0 = (tid >> 3) * 2, vs = (tid & 7) * 8;           // key pair, dh offset
    const u16* Vbase = V + (size_t)vk0 * kv_stride + vs;
    // K fragment base (per-lane direct global loads)
    const u16* Kfb = K + (size_t)c16 * kv_stride + g4 * 8;

    int4 vv0, vv1, kf[8];
    auto load_V = [&](int kt) {
        const u16* vp = Vbase + (size_t)kt * 64 * kv_stride;
        vv0 = *(const int4*)(vp);
        vv1 = *(const int4*)(vp + kv_stride);
    };
    auto load_K = [&](int kt) {
        const u16* kp = Kfb + (size_t)kt * 64 * kv_stride;
#pragma unroll
        for (int nt = 0; nt < 4; nt++) {
            kf[2 * nt]     = *(const int4*)(kp + (size_t)nt * 16 * kv_stride);
            kf[2 * nt + 1] = *(const int4*)(kp + (size_t)nt * 16 * kv_stride + 32);
        }
    };
    auto store_V = [&]() {
        const u16* pa = (const u16*)&vv0;
        const u16* pb = (const u16*)&vv1;
#pragma unroll
        for (int j = 0; j < 8; j++) {
            int dh = vs + j;
            int sw = (dh ^ (dh >> 3)) & 7;
            int off = dh * 64 + ((((vk0 >> 3) ^ sw) << 3) | (vk0 & 7));
            u32 w = (u32)pa[j] | ((u32)pb[j] << 16);
            *(u32*)&lVT[off] = w;
        }
    };

    floatx4 o_acc[4];
#pragma unroll
    for (int d = 0; d < 4; d++) o_acc[d] = (floatx4){0.f, 0.f, 0.f, 0.f};
    float lsum = 0.f;                                       // row sum for qrow = c16
    u16* lPw = lP[wave];
    int swzP = (c16 ^ (c16 >> 3)) & 7;

    int ktend = causal ? (qt + 1) : 32;
    int kt = sp;
    if (kt < ktend) { load_V(kt); load_K(kt); }

    for (; kt < ktend; kt += 4) {
        __syncthreads();           // prior tile's lVT reads complete
        store_V();
        __syncthreads();           // lVT visible

        // S^T = K Q^T from K register fragments (no LDS)
        floatx4 sc[4];
#pragma unroll
        for (int nt = 0; nt < 4; nt++) {
            short8 b0 = *(const short8*)&kf[2 * nt];
            short8 b1 = *(const short8*)&kf[2 * nt + 1];
            floatx4 z = (floatx4){0.f, 0.f, 0.f, 0.f};
            z = __builtin_amdgcn_mfma_f32_16x16x32_bf16(b0, qf0, z, 0, 0, 0);
            z = __builtin_amdgcn_mfma_f32_16x16x32_bf16(b1, qf1, z, 0, 0, 0);
            sc[nt] = z;
        }
        if (kt + 4 < ktend) { load_V(kt + 4); load_K(kt + 4); }   // prefetch next

        if (causal && kt == qt) {
            int qr = qt * 64 + wave * 16 + c16;
#pragma unroll
            for (int nt = 0; nt < 4; nt++) {
                int key0 = kt * 64 + nt * 16 + 4 * g4;
#pragma unroll
                for (int r = 0; r < 4; r++)
                    if (key0 + r > qr) sc[nt][r] = -1e30f;
            }
        }
        // P = exp2(S); per-lane row sum; swizzled b64 writes to per-wave lP (no barrier)
#pragma unroll
        for (int nt = 0; nt < 4; nt++) {
            float p0 = exp2f(sc[nt][0]);
            float p1 = exp2f(sc[nt][1]);
            float p2 = exp2f(sc[nt][2]);
            float p3 = exp2f(sc[nt][3]);
            lsum += (p0 + p1) + (p2 + p3);
            __hip_bfloat162 w0 = __float22bfloat162_rn(make_float2(p0, p1));
            __hip_bfloat162 w1 = __float22bfloat162_rn(make_float2(p2, p3));
            uint2 pk; pk.x = *(u32*)&w0; pk.y = *(u32*)&w1;
            int chunk = 2 * nt + (g4 >> 1);
            *(uint2*)&lPw[c16 * 64 + (((chunk ^ swzP) << 3) | (4 * (g4 & 1)))] = pk;
        }
        // O += P V
        short8 pa0 = *(const short8*)&lPw[c16 * 64 + ((g4 ^ swzP) << 3)];
        short8 pa1 = *(const short8*)&lPw[c16 * 64 + (((g4 + 4) ^ swzP) << 3)];
#pragma unroll
        for (int d = 0; d < 4; d++) {
            int row = d * 16 + c16;
            int swv = (row ^ (row >> 3)) & 7;
            short8 vb0 = *(const short8*)&lVT[row * 64 + ((g4 ^ swv) << 3)];
            short8 vb1 = *(const short8*)&lVT[row * 64 + (((g4 + 4) ^ swv) << 3)];
            o_acc[d] = __builtin_amdgcn_mfma_f32_16x16x32_bf16(pa0, vb0, o_acc[d], 0, 0, 0);
            o_acc[d] = __builtin_amdgcn_mfma_f32_16x16x32_bf16(pa1, vb1, o_acc[d], 0, 0, 0);
        }
    }

    // reduce lsum across the 4 lanes sharing qrow=c16; store partial sum + unnormalized O
    lsum += __shfl_xor(lsum, 16);
    lsum += __shfl_xor(lsum, 32);
    size_t slab = (size_t)(sp * 16 + bh) * 2048;
    if (g4 == 0) Lpart[slab + qrow0 + c16] = lsum;
    float* Ob = Opart + (slab + qrow0) * 64;
#pragma unroll
    for (int d = 0; d < 4; d++)
#pragma unroll
        for (int r = 0; r < 4; r++)
            Ob[(size_t)(4 * g4 + r) * 64 + d * 16 + c16] = o_acc[d][r];
}

// ---------------- combine 4 split partials -> bf16 [4096][512] ----------------
__global__ __launch_bounds__(256) void attn_combine(
    const float4* __restrict__ Op,   // [4][16][2048][16 float4]
    const float* __restrict__ Lp,    // [4][16][2048]
    ushort4* __restrict__ out)       // [4096][128 ushort4]
{
    int e = blockIdx.x * 256 + threadIdx.x;        // 0 .. 524287
    int dh4 = e & 15;
    int qrow = (e >> 4) & 2047;
    int bh = e >> 15;
    int li = bh * 2048 + qrow;
    float l = Lp[li] + Lp[32768 + li] + Lp[65536 + li] + Lp[98304 + li];
    float inv = 1.f / l;
    float4 a = Op[e];
    float4 b = Op[524288 + e];
    float4 c = Op[1048576 + e];
    float4 d = Op[1572864 + e];
    ushort4 o;
    o.x = f2b((a.x + b.x + c.x + d.x) * inv);
    o.y = f2b((a.y + b.y + c.y + d.y) * inv);
    o.z = f2b((a.z + b.z + c.z + d.z) * inv);
    o.w = f2b((a.w + b.w + c.w + d.w) * inv);
    int row = (bh >> 3) * 2048 + qrow;
    out[(size_t)row * 128 + (bh & 7) * 16 + dh4] = o;
}

// ---------------- LayerNorm (row=512), in = in0 (+ in1), emits fp32 and optional bf16 -------
__global__ __launch_bounds__(256) void ln_kernel(const float* __restrict__ in0,
                                                 const float* __restrict__ in1,
                                                 const float* __restrict__ g,
                                                 const float* __restrict__ b,
                                                 float* __restrict__ out_f,
                                                 u16* __restrict__ out_b)
{
    const int D = 512;
    int row = blockIdx.x, tid = threadIdx.x;
    size_t base = (size_t)row * D;
    float v0 = in0[base + tid], v1 = in0[base + tid + 256];
    if (in1) { v0 += in1[base + tid]; v1 += in1[base + tid + 256]; }
    float s = v0 + v1, ss = v0 * v0 + v1 * v1;
#pragma unroll
    for (int off = 1; off < 64; off <<= 1) { s += __shfl_xor(s, off); ss += __shfl_xor(ss, off); }
    __shared__ float red[8];
    int wave = tid >> 6, lane = tid & 63;
    if (lane == 0) { red[wave] = s; red[4 + wave] = ss; }
    __syncthreads();
    float st = red[0] + red[1] + red[2] + red[3];
    float sst = red[4] + red[5] + red[6] + red[7];
    float mu = st * (1.f / 512.f);
    float var = sst * (1.f / 512.f) - mu * mu;
    float rs = rsqrtf(var + 1e-5f);
    float y0 = (v0 - mu) * rs * g[tid] + b[tid];
    float y1 = (v1 - mu) * rs * g[tid + 256] + b[tid + 256];
    if (out_f) { out_f[base + tid] = y0; out_f[base + tid + 256] = y1; }
    if (out_b) { out_b[base + tid] = f2b(y0); out_b[base + tid + 256] = f2b(y1); }
}

// ---------------- launch ----------------
extern "C" void kernel_launch(void* const* d_in, const int* in_sizes, int n_in,
                              void* d_out, int out_size, void* d_ws, size_t ws_size,
                              hipStream_t stream)
{
    (void)in_sizes; (void)n_in; (void)out_size; (void)ws_size;
    const float* x     = (const float*)d_in[0];
    const float* enc   = (const float*)d_in[1];
    const float* m_wq  = (const float*)d_in[2];  const float* m_bq = (const float*)d_in[3];
    const float* m_wk  = (const float*)d_in[4];  const float* m_bk = (const float*)d_in[5];
    const float* m_wv  = (const float*)d_in[6];  const float* m_bv = (const float*)d_in[7];
    const float* m_wo  = (const float*)d_in[8];  const float* m_bo = (const float*)d_in[9];
    const float* c_wq  = (const float*)d_in[10]; const float* c_bq = (const float*)d_in[11];
    const float* c_wk  = (const float*)d_in[12]; const float* c_bk = (const float*)d_in[13];
    const float* c_wv  = (const float*)d_in[14]; const float* c_bv = (const float*)d_in[15];
    const float* c_wo  = (const float*)d_in[16]; const float* c_bo = (const float*)d_in[17];
    const float* ln1_g = (const float*)d_in[18]; const float* ln1_b = (const float*)d_in[19];
    const float* ln2_g = (const float*)d_in[20]; const float* ln2_b = (const float*)d_in[21];
    const float* ln3_g = (const float*)d_in[22]; const float* ln3_b = (const float*)d_in[23];
    const float* ff_w1 = (const float*)d_in[24]; const float* ff_b1 = (const float*)d_in[25];
    const float* ff_w2 = (const float*)d_in[26]; const float* ff_b2 = (const float*)d_in[27];

    char* base = (char*)d_ws; size_t off = 0;
    auto alloc = [&](size_t bytes) -> void* {
        void* p = base + off; off = (off + bytes + 255) & ~(size_t)255; return p;
    };
    u16*   Wqkv_m = (u16*)alloc(1536 * 512 * 2);
    u16*   Wo_m   = (u16*)alloc(512 * 512 * 2);
    u16*   Wq_c   = (u16*)alloc(512 * 512 * 2);
    u16*   Wkv_c  = (u16*)alloc(1024 * 512 * 2);
    u16*   Wo_c   = (u16*)alloc(512 * 512 * 2);
    u16*   W1t    = (u16*)alloc(2048 * 512 * 2);
    u16*   W2t    = (u16*)alloc(512 * 2048 * 2);
    float* bqkv_m = (float*)alloc(1536 * 4);
    float* bkv_c  = (float*)alloc(1024 * 4);
    u16*   xb     = (u16*)alloc((size_t)4096 * 512 * 2);
    u16*   encb   = (u16*)alloc((size_t)4096 * 512 * 2);
    u16*   qkvm   = (u16*)alloc((size_t)4096 * 1536 * 2);
    u16*   attnm  = (u16*)alloc((size_t)4096 * 512 * 2);
    float* y01    = (float*)alloc((size_t)2 * 4096 * 512 * 4);   // K-split partials
    float* x1f    = (float*)alloc((size_t)4096 * 512 * 4);
    u16*   x1b    = (u16*)alloc((size_t)4096 * 512 * 2);
    u16*   qc     = (u16*)alloc((size_t)4096 * 512 * 2);
    u16*   kvc    = (u16*)alloc((size_t)4096 * 1024 * 2);
    u16*   attnc  = (u16*)alloc((size_t)4096 * 512 * 2);
    float* x2f    = (float*)alloc((size_t)4096 * 512 * 4);
    u16*   x2b    = (u16*)alloc((size_t)4096 * 512 * 2);
    u16*   h      = (u16*)alloc((size_t)4096 * 2048 * 2);
    float* Opart  = (float*)alloc((size_t)4 * 16 * 2048 * 64 * 4);
    float* Lpart  = (float*)alloc((size_t)4 * 16 * 2048 * 4);

    // ---- preprocessing: 3 launches ----
    TP16 tp;
    tp.e[0] = {m_wq, Wqkv_m,              512, 512};
    tp.e[1] = {m_wk, Wqkv_m + 512 * 512,  512, 512};
    tp.e[2] = {m_wv, Wqkv_m + 1024 * 512, 512, 512};
    tp.e[3] = {m_wo, Wo_m,                512, 512};
    tp.e[4] = {c_wq, Wq_c,                512, 512};
    tp.e[5] = {c_wk, Wkv_c,               512, 512};
    tp.e[6] = {c_wv, Wkv_c + 512 * 512,   512, 512};
    tp.e[7] = {c_wo, Wo_c,                512, 512};
    for (int k = 0; k < 4; k++)
        tp.e[8 + k]  = {ff_w1 + 512 * k,        W1t + k * 512 * 512, 2048, 512};
    for (int k = 0; k < 4; k++)
        tp.e[12 + k] = {ff_w2 + (size_t)512 * k * 512, W2t + 512 * k, 512, 2048};
    transpose_convert16<<<dim3(16, 16, 16), dim3(32, 8), 0, stream>>>(tp);
    gather_bias<<<10, 256, 0, stream>>>(m_bq, m_bk, m_bv, c_bk, c_bv, bqkv_m, bkv_c);
    cvt_bf16_2<<<2048, 256, 0, stream>>>((const float4*)x, (ushort4*)xb,
                                         (const float4*)enc, (ushort4*)encb);

    // ---- fused QKV_m + KV_c projections (KV_c has no upstream deps) ----
    gemm64x128_dual<<<dim3(64, 20), 256, 0, stream>>>(
        xb, Wqkv_m, bqkv_m, qkvm, 1536, 512,
        encb, Wkv_c, bkv_c, kvc, 1024,
        12, 512, 512, 512);

    // ---- self attention block ----
    attn_fused<<<dim3(32, 16, 4), 256, 0, stream>>>(qkvm, 1536, qkvm + 512, 1536, qkvm + 1024,
                                                    Opart, Lpart, 1);
    attn_combine<<<2048, 256, 0, stream>>>((const float4*)Opart, Lpart, (ushort4*)attnm);
    gemm64x64s<<<dim3(64, 8, 2), 256, 0, stream>>>(attnm, 512, Wo_m, 512, 256,
                                                   m_bo, x, y01, 512);
    ln_kernel<<<4096, 256, 0, stream>>>(y01, y01 + (size_t)4096 * 512, ln1_g, ln1_b, x1f, x1b);

    // ---- cross attention block ----
    gemm64x64<<<dim3(64, 8), 256, 0, stream>>>(x1b, 512, Wq_c, 512, 512,
                                               c_bq, nullptr, nullptr, qc, 512, 512);
    attn_fused<<<dim3(32, 16, 4), 256, 0, stream>>>(qc, 512, kvc, 1024, kvc + 512,
                                                    Opart, Lpart, 0);
    attn_combine<<<2048, 256, 0, stream>>>((const float4*)Opart, Lpart, (ushort4*)attnc);
    gemm64x64s<<<dim3(64, 8, 2), 256, 0, stream>>>(attnc, 512, Wo_c, 512, 256,
                                                   c_bo, x1f, y01, 512);
    ln_kernel<<<4096, 256, 0, stream>>>(y01, y01 + (size_t)4096 * 512, ln2_g, ln2_b, x2f, x2b);

    // ---- feed forward ----
    gemm64x128<<<dim3(64, 16), 256, 0, stream>>>(x2b, 512, W1t, 512, 512,
                                                 ff_b1, nullptr, nullptr, h, 2048, 0, 1);
    gemm64x64s<<<dim3(64, 8, 2), 256, 0, stream>>>(h, 2048, W2t, 2048, 1024,
                                                   ff_b2, x2f, y01, 512);
    ln_kernel<<<4096, 256, 0, stream>>>(y01, y01 + (size_t)4096 * 512, ln3_g, ln3_b,
                                        (float*)d_out, nullptr);
}

// Round 8
// 334.635 us; speedup vs baseline: 1.1864x; 1.1864x over previous
//
#include <hip/hip_runtime.h>
#include <hip/hip_bf16.h>

typedef __attribute__((ext_vector_type(8))) short short8;
typedef __attribute__((ext_vector_type(4))) float floatx4;
typedef unsigned short u16;
typedef unsigned int u32;

#define QSCALE 0.1803368801111244f   // 0.125 * log2(e): folded into Q so softmax is exp2(S)

__device__ __forceinline__ u16 f2b(float f) {
    union { float f; u32 u; } v; v.f = f;
    u32 r = v.u + 0x7fffu + ((v.u >> 16) & 1u);   // RNE
    return (u16)(r >> 16);
}

__device__ __forceinline__ float b2f(u16 b) {
    u32 u = ((u32)b) << 16;
    union { u32 u; float f; } v; v.u = u;
    return v.f;
}

__device__ __forceinline__ void gload(const u16* g, u16* l) {
    __builtin_amdgcn_global_load_lds((const __attribute__((address_space(1))) void*)g,
                                     (__attribute__((address_space(3))) void*)l, 16, 0, 0);
}

// ---------------- batched weight transpose + fp32->bf16 (16 x 512x512 tiles) ----------------
struct TPent { const float* s; u16* d; int O; int dI; };
struct TP16 { TPent e[16]; };
__global__ __launch_bounds__(256) void transpose_convert16(TP16 p) {
    __shared__ float t[32][33];
    TPent e = p.e[blockIdx.z];
    int o0 = blockIdx.x * 32, i0 = blockIdx.y * 32;
    int tx = threadIdx.x, ty = threadIdx.y;
#pragma unroll
    for (int k = 0; k < 32; k += 8) t[ty + k][tx] = e.s[(size_t)(i0 + ty + k) * e.O + o0 + tx];
    __syncthreads();
#pragma unroll
    for (int k = 0; k < 32; k += 8) e.d[(size_t)(o0 + ty + k) * e.dI + i0 + tx] = f2b(t[tx][ty + k]);
}

// gather 5 bias vectors into 2 concat buffers. grid 10 x 256
__global__ __launch_bounds__(256) void gather_bias(const float* b0, const float* b1, const float* b2,
                                                   const float* b3, const float* b4,
                                                   float* dqkv, float* dkv) {
    int i = blockIdx.x * 256 + threadIdx.x;
    if      (i < 512)  dqkv[i] = b0[i];
    else if (i < 1024) dqkv[i] = b1[i - 512];
    else if (i < 1536) dqkv[i] = b2[i - 1024];
    else if (i < 2048) dkv[i - 1536] = b3[i - 1536];
    else               dkv[i - 1536] = b4[i - 2048];
}

// fp32 -> bf16 for x and enc in one launch. grid 2048 x 256, 4 elems each.
__global__ __launch_bounds__(256) void cvt_bf16_2(const float4* __restrict__ s0, ushort4* __restrict__ d0,
                                                  const float4* __restrict__ s1, ushort4* __restrict__ d1) {
    int i = blockIdx.x * 256 + threadIdx.x;
    float4 v = s0[i];
    ushort4 o; o.x = f2b(v.x); o.y = f2b(v.y); o.z = f2b(v.z); o.w = f2b(v.w);
    d0[i] = o;
    v = s1[i];
    o.x = f2b(v.x); o.y = f2b(v.y); o.z = f2b(v.z); o.w = f2b(v.w);
    d1[i] = o;
}

// ---------------- GEMM 64x128: C = A[M,K] @ Bt[N,K] + epilogue. grid (M/64, N/128) ----------------
__global__ __launch_bounds__(256) void gemm64x128(
    const u16* __restrict__ A, int lda,
    const u16* __restrict__ B, int ldb,
    int K,
    const float* __restrict__ bias,
    const float* __restrict__ residual,
    float* __restrict__ out_f, u16* __restrict__ out_b,
    int out_stride, int scale_ncols, int gelu_flag)
{
    __shared__ u16 lA[64 * 32];
    __shared__ u16 lB[128 * 32];
    int tid = threadIdx.x, wave = tid >> 6, lane = tid & 63;
    int g4 = lane >> 4, c16 = lane & 15;
    int bm = blockIdx.x * 64, bn = blockIdx.y * 128;
    int wm = (wave >> 1) * 32, wn = (wave & 1) * 64;
    int srow = tid >> 2, skseg = (tid & 3) * 8;
    const u16* Ar = A + (size_t)(bm + srow) * lda + skseg;
    const u16* Br = B + (size_t)(bn + srow) * ldb + skseg;
    size_t b64o = (size_t)64 * ldb;

    floatx4 acc[2][4];
#pragma unroll
    for (int i = 0; i < 2; i++)
#pragma unroll
        for (int j = 0; j < 4; j++) acc[i][j] = (floatx4){0.f, 0.f, 0.f, 0.f};

    for (int kt = 0; kt < K; kt += 32) {
        __syncthreads();
        gload(Ar + kt,        lA + wave * 512);
        gload(Br + kt,        lB + wave * 512);
        gload(Br + kt + b64o, lB + 2048 + wave * 512);
        __syncthreads();
        short8 aF[2], bF[4];
#pragma unroll
        for (int i = 0; i < 2; i++) aF[i] = *(const short8*)&lA[(wm + i * 16 + c16) * 32 + g4 * 8];
#pragma unroll
        for (int j = 0; j < 4; j++) bF[j] = *(const short8*)&lB[(wn + j * 16 + c16) * 32 + g4 * 8];
#pragma unroll
        for (int i = 0; i < 2; i++)
#pragma unroll
            for (int j = 0; j < 4; j++)
                acc[i][j] = __builtin_amdgcn_mfma_f32_16x16x32_bf16(aF[i], bF[j], acc[i][j], 0, 0, 0);
    }

#pragma unroll
    for (int i = 0; i < 2; i++) {
        int row0 = bm + wm + i * 16 + g4 * 4;
#pragma unroll
        for (int j = 0; j < 4; j++) {
            int col = bn + wn + j * 16 + c16;
            float bv = bias[col];
#pragma unroll
            for (int r = 0; r < 4; r++) {
                int row = row0 + r;
                float v = acc[i][j][r] + bv;
                if (col < scale_ncols) v *= QSCALE;
                if (gelu_flag) v = 0.5f * v * (1.f + erff(v * 0.70710678118654752f));
                if (residual) v += residual[(size_t)row * out_stride + col];
                if (out_f) out_f[(size_t)row * out_stride + col] = v;
                else       out_b[(size_t)row * out_stride + col] = f2b(v);
            }
        }
    }
}

// ---------------- dual GEMM 64x128 (QKV_m for by<ys, KV_c for by>=ys), bf16 out ----------------
__global__ __launch_bounds__(256) void gemm64x128_dual(
    const u16* __restrict__ A0, const u16* __restrict__ B0, const float* __restrict__ bias0,
    u16* __restrict__ out0, int ostride0, int scale0,
    const u16* __restrict__ A1, const u16* __restrict__ B1, const float* __restrict__ bias1,
    u16* __restrict__ out1, int ostride1,
    int ys, int K, int lda, int ldb)
{
    __shared__ u16 lA[64 * 32];
    __shared__ u16 lB[128 * 32];
    int tid = threadIdx.x, wave = tid >> 6, lane = tid & 63;
    int g4 = lane >> 4, c16 = lane & 15;
    int by = blockIdx.y;
    const u16* A; const u16* B; const float* bias; u16* out; int ostride, scaleN, bn;
    if (by < ys) { A = A0; B = B0; bias = bias0; out = out0; ostride = ostride0; scaleN = scale0; bn = by * 128; }
    else         { A = A1; B = B1; bias = bias1; out = out1; ostride = ostride1; scaleN = 0;      bn = (by - ys) * 128; }
    int bm = blockIdx.x * 64;
    int wm = (wave >> 1) * 32, wn = (wave & 1) * 64;
    int srow = tid >> 2, skseg = (tid & 3) * 8;
    const u16* Ar = A + (size_t)(bm + srow) * lda + skseg;
    const u16* Br = B + (size_t)(bn + srow) * ldb + skseg;
    size_t b64o = (size_t)64 * ldb;

    floatx4 acc[2][4];
#pragma unroll
    for (int i = 0; i < 2; i++)
#pragma unroll
        for (int j = 0; j < 4; j++) acc[i][j] = (floatx4){0.f, 0.f, 0.f, 0.f};

    for (int kt = 0; kt < K; kt += 32) {
        __syncthreads();
        gload(Ar + kt,        lA + wave * 512);
        gload(Br + kt,        lB + wave * 512);
        gload(Br + kt + b64o, lB + 2048 + wave * 512);
        __syncthreads();
        short8 aF[2], bF[4];
#pragma unroll
        for (int i = 0; i < 2; i++) aF[i] = *(const short8*)&lA[(wm + i * 16 + c16) * 32 + g4 * 8];
#pragma unroll
        for (int j = 0; j < 4; j++) bF[j] = *(const short8*)&lB[(wn + j * 16 + c16) * 32 + g4 * 8];
#pragma unroll
        for (int i = 0; i < 2; i++)
#pragma unroll
            for (int j = 0; j < 4; j++)
                acc[i][j] = __builtin_amdgcn_mfma_f32_16x16x32_bf16(aF[i], bF[j], acc[i][j], 0, 0, 0);
    }

#pragma unroll
    for (int i = 0; i < 2; i++) {
        int row0 = bm + wm + i * 16 + g4 * 4;
#pragma unroll
        for (int j = 0; j < 4; j++) {
            int col = bn + wn + j * 16 + c16;
            float bv = bias[col];
#pragma unroll
            for (int r = 0; r < 4; r++) {
                float v = acc[i][j][r] + bv;
                if (col < scaleN) v *= QSCALE;
                out[(size_t)(row0 + r) * ostride + col] = f2b(v);
            }
        }
    }
}

// ---------------- GEMM 64x64, bf16/fp32 out, single-pass (used for Q_c) ----------------
__global__ __launch_bounds__(256) void gemm64x64(
    const u16* __restrict__ A, int lda,
    const u16* __restrict__ B, int ldb,
    int K,
    const float* __restrict__ bias,
    const float* __restrict__ residual,
    float* __restrict__ out_f, u16* __restrict__ out_b,
    int out_stride, int scale_ncols)
{
    __shared__ u16 lA[64 * 32];
    __shared__ u16 lB[64 * 32];
    int tid = threadIdx.x, wave = tid >> 6, lane = tid & 63;
    int g4 = lane >> 4, c16 = lane & 15;
    int bm = blockIdx.x * 64, bn = blockIdx.y * 64;
    int wm = wave * 16;
    int srow = tid >> 2, skseg = (tid & 3) * 8;
    const u16* Ar = A + (size_t)(bm + srow) * lda + skseg;
    const u16* Br = B + (size_t)(bn + srow) * ldb + skseg;

    floatx4 acc[4];
#pragma unroll
    for (int j = 0; j < 4; j++) acc[j] = (floatx4){0.f, 0.f, 0.f, 0.f};

    for (int kt = 0; kt < K; kt += 32) {
        __syncthreads();
        gload(Ar + kt, lA + wave * 512);
        gload(Br + kt, lB + wave * 512);
        __syncthreads();
        short8 aF = *(const short8*)&lA[(wm + c16) * 32 + g4 * 8];
        short8 bF[4];
#pragma unroll
        for (int j = 0; j < 4; j++) bF[j] = *(const short8*)&lB[(j * 16 + c16) * 32 + g4 * 8];
#pragma unroll
        for (int j = 0; j < 4; j++)
            acc[j] = __builtin_amdgcn_mfma_f32_16x16x32_bf16(aF, bF[j], acc[j], 0, 0, 0);
    }

    int row0 = bm + wm + g4 * 4;
#pragma unroll
    for (int j = 0; j < 4; j++) {
        int col = bn + j * 16 + c16;
        float bv = bias[col];
#pragma unroll
        for (int r = 0; r < 4; r++) {
            int row = row0 + r;
            float v = acc[j][r] + bv;
            if (col < scale_ncols) v *= QSCALE;
            if (residual) v += residual[(size_t)row * out_stride + col];
            if (out_f) out_f[(size_t)row * out_stride + col] = v;
            else       out_b[(size_t)row * out_stride + col] = f2b(v);
        }
    }
}

// ---------------- GEMM 64x64 K-split-2: fp32 partials. grid (M/64, N/64, 2) ----------------
__global__ __launch_bounds__(256) void gemm64x64s(
    const u16* __restrict__ A, int lda,
    const u16* __restrict__ B, int ldb,
    int Ksub,
    const float* __restrict__ bias,
    const float* __restrict__ residual,
    float* __restrict__ out0, int out_stride)
{
    __shared__ u16 lA[64 * 32];
    __shared__ u16 lB[64 * 32];
    int tid = threadIdx.x, wave = tid >> 6, lane = tid & 63;
    int g4 = lane >> 4, c16 = lane & 15;
    int bm = blockIdx.x * 64, bn = blockIdx.y * 64, sp = blockIdx.z;
    int wm = wave * 16;
    int srow = tid >> 2, skseg = (tid & 3) * 8 + sp * Ksub;
    const u16* Ar = A + (size_t)(bm + srow) * lda + skseg;
    const u16* Br = B + (size_t)(bn + srow) * ldb + skseg;

    floatx4 acc[4];
#pragma unroll
    for (int j = 0; j < 4; j++) acc[j] = (floatx4){0.f, 0.f, 0.f, 0.f};

    for (int kt = 0; kt < Ksub; kt += 32) {
        __syncthreads();
        gload(Ar + kt, lA + wave * 512);
        gload(Br + kt, lB + wave * 512);
        __syncthreads();
        short8 aF = *(const short8*)&lA[(wm + c16) * 32 + g4 * 8];
        short8 bF[4];
#pragma unroll
        for (int j = 0; j < 4; j++) bF[j] = *(const short8*)&lB[(j * 16 + c16) * 32 + g4 * 8];
#pragma unroll
        for (int j = 0; j < 4; j++)
            acc[j] = __builtin_amdgcn_mfma_f32_16x16x32_bf16(aF, bF[j], acc[j], 0, 0, 0);
    }

    float* out = out0 + (size_t)sp * 4096 * 512;
    int row0 = bm + wm + g4 * 4;
#pragma unroll
    for (int j = 0; j < 4; j++) {
        int col = bn + j * 16 + c16;
        float bv = (sp == 0) ? bias[col] : 0.f;
#pragma unroll
        for (int r = 0; r < 4; r++) {
            int row = row0 + r;
            float v = acc[j][r] + bv;
            if (sp == 0 && residual) v += residual[(size_t)row * out_stride + col];
            out[(size_t)row * out_stride + col] = v;
        }
    }
}

// ---------------- flash attention (R4/R6 proven body): 64-row Q-tile, 2-way key split -------
// grid (32 q-tiles, B*H, 2 splits), block 256. Split s: tiles {s, s+2, ...}.
// No max-subtraction -> partials combine exactly. bf16 unnormalized O partials + fp32 row sums.
__global__ __launch_bounds__(256) void attn_fused(
    const u16* __restrict__ Qp, int q_stride,
    const u16* __restrict__ Kp, int kv_stride,
    const u16* __restrict__ Vp,
    u16* __restrict__ Opart,     // [2][16][2048][64] bf16
    float* __restrict__ Lpart,   // [2][16][2048]
    int causal)
{
    __shared__ u16 lK[64 * 72];    // [key][dh]
    __shared__ u16 lVT[64 * 72];   // [dh][key^swz]
    __shared__ u16 lP[4 * 16 * 72];// per-wave private [qrow][key]
    int tid = threadIdx.x, wave = tid >> 6, lane = tid & 63;
    int g4 = lane >> 4, c16 = lane & 15;
    int qt = blockIdx.x, bh = blockIdx.y, sp = blockIdx.z;
    size_t rowbase = (size_t)(bh >> 3) * 2048;
    int hoff = (bh & 7) * 64;
    const u16* Q = Qp + rowbase * q_stride + hoff;
    const u16* K = Kp + rowbase * kv_stride + hoff;
    const u16* V = Vp + rowbase * kv_stride + hoff;

    int qrow0 = qt * 64 + wave * 16;
    short8 qf0 = *(const short8*)&Q[(size_t)(qrow0 + c16) * q_stride + g4 * 8];
    short8 qf1 = *(const short8*)&Q[(size_t)(qrow0 + c16) * q_stride + g4 * 8 + 32];

    // staging addresses
    int kr = tid >> 2, ks = (tid & 3) * 16;                 // K: row, u16 col offset
    const u16* Kbase = K + (size_t)kr * kv_stride + ks;
    int vk0 = (tid >> 3) * 2, vs = (tid & 7) * 8;           // V: key pair, dh offset
    const u16* Vbase = V + (size_t)vk0 * kv_stride + vs;

    int4 kv0, kv1, vv0, vv1;
    auto load_tile = [&](int kt) {
        const u16* kp = Kbase + (size_t)kt * 64 * kv_stride;
        kv0 = *(const int4*)(kp);
        kv1 = *(const int4*)(kp + 8);
        const u16* vp = Vbase + (size_t)kt * 64 * kv_stride;
        vv0 = *(const int4*)(vp);
        vv1 = *(const int4*)(vp + kv_stride);
    };
    auto store_tile = [&]() {
        *(int4*)&lK[kr * 72 + ks] = kv0;
        *(int4*)&lK[kr * 72 + ks + 8] = kv1;
        const u16* pa = (const u16*)&vv0;
        const u16* pb = (const u16*)&vv1;
#pragma unroll
        for (int j = 0; j < 8; j++) {
            int dh = vs + j;
            int keyS = vk0 ^ (((dh >> 3) & 3) << 4);       // XOR swizzle kills 8-way bank conflict
            u32 w = (u32)pa[j] | ((u32)pb[j] << 16);
            *(u32*)&lVT[dh * 72 + keyS] = w;
        }
    };

    floatx4 o_acc[4];
#pragma unroll
    for (int d = 0; d < 4; d++) o_acc[d] = (floatx4){0.f, 0.f, 0.f, 0.f};
    float lsum = 0.f;                                       // row sum for qrow = c16
    u16* lPw = lP + wave * 1152;

    int ktend = causal ? (qt + 1) : 32;
    int kt = sp;
    if (kt < ktend) load_tile(kt);

    for (; kt < ktend; kt += 2) {
        __syncthreads();           // prior tile's LDS reads complete
        store_tile();
        __syncthreads();           // staging visible
        if (kt + 2 < ktend) load_tile(kt + 2);   // prefetch overlaps compute

        // S^T = K Q^T : lane holds qrow=c16, keys nt*16 + 4*g4 + r (key-contiguous)
        floatx4 sc[4];
#pragma unroll
        for (int nt = 0; nt < 4; nt++) {
            short8 b0 = *(const short8*)&lK[(nt * 16 + c16) * 72 + g4 * 8];
            short8 b1 = *(const short8*)&lK[(nt * 16 + c16) * 72 + g4 * 8 + 32];
            floatx4 z = (floatx4){0.f, 0.f, 0.f, 0.f};
            z = __builtin_amdgcn_mfma_f32_16x16x32_bf16(b0, qf0, z, 0, 0, 0);
            z = __builtin_amdgcn_mfma_f32_16x16x32_bf16(b1, qf1, z, 0, 0, 0);
            sc[nt] = z;
        }
        if (causal && kt == qt) {
            int qr = qt * 64 + wave * 16 + c16;
#pragma unroll
            for (int nt = 0; nt < 4; nt++) {
                int key0 = kt * 64 + nt * 16 + 4 * g4;
#pragma unroll
                for (int r = 0; r < 4; r++)
                    if (key0 + r > qr) sc[nt][r] = -1e30f;
            }
        }
        // P = exp2(S); per-lane row sum; b64 writes to per-wave lP (no barrier)
#pragma unroll
        for (int nt = 0; nt < 4; nt++) {
            float p0 = exp2f(sc[nt][0]);
            float p1 = exp2f(sc[nt][1]);
            float p2 = exp2f(sc[nt][2]);
            float p3 = exp2f(sc[nt][3]);
            lsum += (p0 + p1) + (p2 + p3);
            __hip_bfloat162 w0 = __float22bfloat162_rn(make_float2(p0, p1));
            __hip_bfloat162 w1 = __float22bfloat162_rn(make_float2(p2, p3));
            uint2 pk; pk.x = *(u32*)&w0; pk.y = *(u32*)&w1;
            *(uint2*)&lPw[c16 * 72 + nt * 16 + 4 * g4] = pk;
        }
        // O += P V
        short8 pa0 = *(const short8*)&lPw[c16 * 72 + g4 * 8];
        short8 pa1 = *(const short8*)&lPw[c16 * 72 + g4 * 8 + 32];
#pragma unroll
        for (int d = 0; d < 4; d++) {
            int swz = ((2 * d + (c16 >> 3)) & 3) << 4;
            short8 vb0 = *(const short8*)&lVT[(d * 16 + c16) * 72 + ((g4 * 8) ^ swz)];
            short8 vb1 = *(const short8*)&lVT[(d * 16 + c16) * 72 + ((32 + g4 * 8) ^ swz)];
            o_acc[d] = __builtin_amdgcn_mfma_f32_16x16x32_bf16(pa0, vb0, o_acc[d], 0, 0, 0);
            o_acc[d] = __builtin_amdgcn_mfma_f32_16x16x32_bf16(pa1, vb1, o_acc[d], 0, 0, 0);
        }
    }

    // reduce lsum across the 4 lanes sharing qrow=c16; store partial sum + unnormalized bf16 O
    lsum += __shfl_xor(lsum, 16);
    lsum += __shfl_xor(lsum, 32);
    size_t slab = (size_t)(sp * 16 + bh) * 2048;
    if (g4 == 0) Lpart[slab + qrow0 + c16] = lsum;
    u16* Ob = Opart + (slab + qrow0) * 64;
#pragma unroll
    for (int d = 0; d < 4; d++)
#pragma unroll
        for (int r = 0; r < 4; r++)
            Ob[(size_t)(4 * g4 + r) * 64 + d * 16 + c16] = f2b(o_acc[d][r]);
}

// ---------------- combine 2 bf16 split partials -> bf16 [4096][512] ----------------
// grid 2048 x 256; each thread: 4 dh of one (bh,row).
__global__ __launch_bounds__(256) void attn_combine(
    const ushort4* __restrict__ Op,  // [2][16][2048][16 ushort4]
    const float* __restrict__ Lp,    // [2][16][2048]
    ushort4* __restrict__ out)       // [4096][128 ushort4]
{
    int e = blockIdx.x * 256 + threadIdx.x;        // 0 .. 524287
    int dh4 = e & 15;
    int qrow = (e >> 4) & 2047;
    int bh = e >> 15;
    int li = bh * 2048 + qrow;
    float l = Lp[li] + Lp[32768 + li];
    float inv = 1.f / l;
    ushort4 a = Op[e];
    ushort4 b = Op[524288 + e];
    ushort4 o;
    o.x = f2b((b2f(a.x) + b2f(b.x)) * inv);
    o.y = f2b((b2f(a.y) + b2f(b.y)) * inv);
    o.z = f2b((b2f(a.z) + b2f(b.z)) * inv);
    o.w = f2b((b2f(a.w) + b2f(b.w)) * inv);
    int row = (bh >> 3) * 2048 + qrow;
    out[(size_t)row * 128 + (bh & 7) * 16 + dh4] = o;
}

// ---------------- LayerNorm (row=512), in = in0 (+ in1), emits fp32 and optional bf16 -------
__global__ __launch_bounds__(256) void ln_kernel(const float* __restrict__ in0,
                                                 const float* __restrict__ in1,
                                                 const float* __restrict__ g,
                                                 const float* __restrict__ b,
                                                 float* __restrict__ out_f,
                                                 u16* __restrict__ out_b)
{
    const int D = 512;
    int row = blockIdx.x, tid = threadIdx.x;
    size_t base = (size_t)row * D;
    float v0 = in0[base + tid], v1 = in0[base + tid + 256];
    if (in1) { v0 += in1[base + tid]; v1 += in1[base + tid + 256]; }
    float s = v0 + v1, ss = v0 * v0 + v1 * v1;
#pragma unroll
    for (int off = 1; off < 64; off <<= 1) { s += __shfl_xor(s, off); ss += __shfl_xor(ss, off); }
    __shared__ float red[8];
    int wave = tid >> 6, lane = tid & 63;
    if (lane == 0) { red[wave] = s; red[4 + wave] = ss; }
    __syncthreads();
    float st = red[0] + red[1] + red[2] + red[3];
    float sst = red[4] + red[5] + red[6] + red[7];
    float mu = st * (1.f / 512.f);
    float var = sst * (1.f / 512.f) - mu * mu;
    float rs = rsqrtf(var + 1e-5f);
    float y0 = (v0 - mu) * rs * g[tid] + b[tid];
    float y1 = (v1 - mu) * rs * g[tid + 256] + b[tid + 256];
    if (out_f) { out_f[base + tid] = y0; out_f[base + tid + 256] = y1; }
    if (out_b) { out_b[base + tid] = f2b(y0); out_b[base + tid + 256] = f2b(y1); }
}

// ---------------- launch ----------------
extern "C" void kernel_launch(void* const* d_in, const int* in_sizes, int n_in,
                              void* d_out, int out_size, void* d_ws, size_t ws_size,
                              hipStream_t stream)
{
    (void)in_sizes; (void)n_in; (void)out_size; (void)ws_size;
    const float* x     = (const float*)d_in[0];
    const float* enc   = (const float*)d_in[1];
    const float* m_wq  = (const float*)d_in[2];  const float* m_bq = (const float*)d_in[3];
    const float* m_wk  = (const float*)d_in[4];  const float* m_bk = (const float*)d_in[5];
    const float* m_wv  = (const float*)d_in[6];  const float* m_bv = (const float*)d_in[7];
    const float* m_wo  = (const float*)d_in[8];  const float* m_bo = (const float*)d_in[9];
    const float* c_wq  = (const float*)d_in[10]; const float* c_bq = (const float*)d_in[11];
    const float* c_wk  = (const float*)d_in[12]; const float* c_bk = (const float*)d_in[13];
    const float* c_wv  = (const float*)d_in[14]; const float* c_bv = (const float*)d_in[15];
    const float* c_wo  = (const float*)d_in[16]; const float* c_bo = (const float*)d_in[17];
    const float* ln1_g = (const float*)d_in[18]; const float* ln1_b = (const float*)d_in[19];
    const float* ln2_g = (const float*)d_in[20]; const float* ln2_b = (const float*)d_in[21];
    const float* ln3_g = (const float*)d_in[22]; const float* ln3_b = (const float*)d_in[23];
    const float* ff_w1 = (const float*)d_in[24]; const float* ff_b1 = (const float*)d_in[25];
    const float* ff_w2 = (const float*)d_in[26]; const float* ff_b2 = (const float*)d_in[27];

    char* base = (char*)d_ws; size_t off = 0;
    auto alloc = [&](size_t bytes) -> void* {
        void* p = base + off; off = (off + bytes + 255) & ~(size_t)255; return p;
    };
    u16*   Wqkv_m = (u16*)alloc(1536 * 512 * 2);
    u16*   Wo_m   = (u16*)alloc(512 * 512 * 2);
    u16*   Wq_c   = (u16*)alloc(512 * 512 * 2);
    u16*   Wkv_c  = (u16*)alloc(1024 * 512 * 2);
    u16*   Wo_c   = (u16*)alloc(512 * 512 * 2);
    u16*   W1t    = (u16*)alloc(2048 * 512 * 2);
    u16*   W2t    = (u16*)alloc(512 * 2048 * 2);
    float* bqkv_m = (float*)alloc(1536 * 4);
    float* bkv_c  = (float*)alloc(1024 * 4);
    u16*   xb     = (u16*)alloc((size_t)4096 * 512 * 2);
    u16*   encb   = (u16*)alloc((size_t)4096 * 512 * 2);
    u16*   qkvm   = (u16*)alloc((size_t)4096 * 1536 * 2);
    u16*   attnm  = (u16*)alloc((size_t)4096 * 512 * 2);
    float* y01    = (float*)alloc((size_t)2 * 4096 * 512 * 4);   // K-split partials
    float* x1f    = (float*)alloc((size_t)4096 * 512 * 4);
    u16*   x1b    = (u16*)alloc((size_t)4096 * 512 * 2);
    u16*   qc     = (u16*)alloc((size_t)4096 * 512 * 2);
    u16*   kvc    = (u16*)alloc((size_t)4096 * 1024 * 2);
    u16*   attnc  = (u16*)alloc((size_t)4096 * 512 * 2);
    float* x2f    = (float*)alloc((size_t)4096 * 512 * 4);
    u16*   x2b    = (u16*)alloc((size_t)4096 * 512 * 2);
    u16*   h      = (u16*)alloc((size_t)4096 * 2048 * 2);
    u16*   Opart  = (u16*)alloc((size_t)2 * 16 * 2048 * 64 * 2);
    float* Lpart  = (float*)alloc((size_t)2 * 16 * 2048 * 4);

    // ---- preprocessing: 3 launches ----
    TP16 tp;
    tp.e[0] = {m_wq, Wqkv_m,              512, 512};
    tp.e[1] = {m_wk, Wqkv_m + 512 * 512,  512, 512};
    tp.e[2] = {m_wv, Wqkv_m + 1024 * 512, 512, 512};
    tp.e[3] = {m_wo, Wo_m,                512, 512};
    tp.e[4] = {c_wq, Wq_c,                512, 512};
    tp.e[5] = {c_wk, Wkv_c,               512, 512};
    tp.e[6] = {c_wv, Wkv_c + 512 * 512,   512, 512};
    tp.e[7] = {c_wo, Wo_c,                512, 512};
    for (int k = 0; k < 4; k++)
        tp.e[8 + k]  = {ff_w1 + 512 * k,        W1t + k * 512 * 512, 2048, 512};
    for (int k = 0; k < 4; k++)
        tp.e[12 + k] = {ff_w2 + (size_t)512 * k * 512, W2t + 512 * k, 512, 2048};
    transpose_convert16<<<dim3(16, 16, 16), dim3(32, 8), 0, stream>>>(tp);
    gather_bias<<<10, 256, 0, stream>>>(m_bq, m_bk, m_bv, c_bk, c_bv, bqkv_m, bkv_c);
    cvt_bf16_2<<<2048, 256, 0, stream>>>((const float4*)x, (ushort4*)xb,
                                         (const float4*)enc, (ushort4*)encb);

    // ---- fused QKV_m + KV_c projections (KV_c has no upstream deps) ----
    gemm64x128_dual<<<dim3(64, 20), 256, 0, stream>>>(
        xb, Wqkv_m, bqkv_m, qkvm, 1536, 512,
        encb, Wkv_c, bkv_c, kvc, 1024,
        12, 512, 512, 512);

    // ---- self attention block ----
    attn_fused<<<dim3(32, 16, 2), 256, 0, stream>>>(qkvm, 1536, qkvm + 512, 1536, qkvm + 1024,
                                                    Opart, Lpart, 1);
    attn_combine<<<2048, 256, 0, stream>>>((const ushort4*)Opart, Lpart, (ushort4*)attnm);
    gemm64x64s<<<dim3(64, 8, 2), 256, 0, stream>>>(attnm, 512, Wo_m, 512, 256,
                                                   m_bo, x, y01, 512);
    ln_kernel<<<4096, 256, 0, stream>>>(y01, y01 + (size_t)4096 * 512, ln1_g, ln1_b, x1f, x1b);

    // ---- cross attention block ----
    gemm64x64<<<dim3(64, 8), 256, 0, stream>>>(x1b, 512, Wq_c, 512, 512,
                                               c_bq, nullptr, nullptr, qc, 512, 512);
    attn_fused<<<dim3(32, 16, 2), 256, 0, stream>>>(qc, 512, kvc, 1024, kvc + 512,
                                                    Opart, Lpart, 0);
    attn_combine<<<2048, 256, 0, stream>>>((const ushort4*)Opart, Lpart, (ushort4*)attnc);
    gemm64x64s<<<dim3(64, 8, 2), 256, 0, stream>>>(attnc, 512, Wo_c, 512, 256,
                                                   c_bo, x1f, y01, 512);
    ln_kernel<<<4096, 256, 0, stream>>>(y01, y01 + (size_t)4096 * 512, ln2_g, ln2_b, x2f, x2b);

    // ---- feed forward ----
    gemm64x128<<<dim3(64, 16), 256, 0, stream>>>(x2b, 512, W1t, 512, 512,
                                                 ff_b1, nullptr, nullptr, h, 2048, 0, 1);
    gemm64x64s<<<dim3(64, 8, 2), 256, 0, stream>>>(h, 2048, W2t, 2048, 1024,
                                                   ff_b2, x2f, y01, 512);
    ln_kernel<<<4096, 256, 0, stream>>>(y01, y01 + (size_t)4096 * 512, ln3_g, ln3_b,
                                        (float*)d_out, nullptr);
}

// Round 9
// 334.060 us; speedup vs baseline: 1.1884x; 1.0017x over previous
//
#include <hip/hip_runtime.h>
#include <hip/hip_bf16.h>

typedef __attribute__((ext_vector_type(8))) short short8;
typedef __attribute__((ext_vector_type(4))) float floatx4;
typedef unsigned short u16;
typedef unsigned int u32;

#define QSCALE 0.1803368801111244f   // 0.125 * log2(e): folded into Q so softmax is exp2(S)

__device__ __forceinline__ u16 f2b(float f) {
    union { float f; u32 u; } v; v.f = f;
    u32 r = v.u + 0x7fffu + ((v.u >> 16) & 1u);   // RNE
    return (u16)(r >> 16);
}

__device__ __forceinline__ float b2f(u16 b) {
    u32 u = ((u32)b) << 16;
    union { u32 u; float f; } v; v.u = u;
    return v.f;
}

__device__ __forceinline__ void gload(const u16* g, u16* l) {
    __builtin_amdgcn_global_load_lds((const __attribute__((address_space(1))) void*)g,
                                     (__attribute__((address_space(3))) void*)l, 16, 0, 0);
}

// ---------------- batched weight transpose + fp32->bf16 (16 x 512x512 tiles) ----------------
struct TPent { const float* s; u16* d; int O; int dI; };
struct TP16 { TPent e[16]; };
__global__ __launch_bounds__(256) void transpose_convert16(TP16 p) {
    __shared__ float t[32][33];
    TPent e = p.e[blockIdx.z];
    int o0 = blockIdx.x * 32, i0 = blockIdx.y * 32;
    int tx = threadIdx.x, ty = threadIdx.y;
#pragma unroll
    for (int k = 0; k < 32; k += 8) t[ty + k][tx] = e.s[(size_t)(i0 + ty + k) * e.O + o0 + tx];
    __syncthreads();
#pragma unroll
    for (int k = 0; k < 32; k += 8) e.d[(size_t)(o0 + ty + k) * e.dI + i0 + tx] = f2b(t[tx][ty + k]);
}

// gather 5 bias vectors into 2 concat buffers. grid 10 x 256
__global__ __launch_bounds__(256) void gather_bias(const float* b0, const float* b1, const float* b2,
                                                   const float* b3, const float* b4,
                                                   float* dqkv, float* dkv) {
    int i = blockIdx.x * 256 + threadIdx.x;
    if      (i < 512)  dqkv[i] = b0[i];
    else if (i < 1024) dqkv[i] = b1[i - 512];
    else if (i < 1536) dqkv[i] = b2[i - 1024];
    else if (i < 2048) dkv[i - 1536] = b3[i - 1536];
    else               dkv[i - 1536] = b4[i - 2048];
}

// fp32 -> bf16 for x and enc in one launch. grid 2048 x 256, 4 elems each.
__global__ __launch_bounds__(256) void cvt_bf16_2(const float4* __restrict__ s0, ushort4* __restrict__ d0,
                                                  const float4* __restrict__ s1, ushort4* __restrict__ d1) {
    int i = blockIdx.x * 256 + threadIdx.x;
    float4 v = s0[i];
    ushort4 o; o.x = f2b(v.x); o.y = f2b(v.y); o.z = f2b(v.z); o.w = f2b(v.w);
    d0[i] = o;
    v = s1[i];
    o.x = f2b(v.x); o.y = f2b(v.y); o.z = f2b(v.z); o.w = f2b(v.w);
    d1[i] = o;
}

// ---------------- GEMM 64x128: C = A[M,K] @ Bt[N,K] + epilogue. grid (M/64, N/128) ----------------
__global__ __launch_bounds__(256) void gemm64x128(
    const u16* __restrict__ A, int lda,
    const u16* __restrict__ B, int ldb,
    int K,
    const float* __restrict__ bias,
    const float* __restrict__ residual,
    float* __restrict__ out_f, u16* __restrict__ out_b,
    int out_stride, int scale_ncols, int gelu_flag)
{
    __shared__ u16 lA[64 * 32];
    __shared__ u16 lB[128 * 32];
    int tid = threadIdx.x, wave = tid >> 6, lane = tid & 63;
    int g4 = lane >> 4, c16 = lane & 15;
    int bm = blockIdx.x * 64, bn = blockIdx.y * 128;
    int wm = (wave >> 1) * 32, wn = (wave & 1) * 64;
    int srow = tid >> 2, skseg = (tid & 3) * 8;
    const u16* Ar = A + (size_t)(bm + srow) * lda + skseg;
    const u16* Br = B + (size_t)(bn + srow) * ldb + skseg;
    size_t b64o = (size_t)64 * ldb;

    floatx4 acc[2][4];
#pragma unroll
    for (int i = 0; i < 2; i++)
#pragma unroll
        for (int j = 0; j < 4; j++) acc[i][j] = (floatx4){0.f, 0.f, 0.f, 0.f};

    for (int kt = 0; kt < K; kt += 32) {
        __syncthreads();
        gload(Ar + kt,        lA + wave * 512);
        gload(Br + kt,        lB + wave * 512);
        gload(Br + kt + b64o, lB + 2048 + wave * 512);
        __syncthreads();
        short8 aF[2], bF[4];
#pragma unroll
        for (int i = 0; i < 2; i++) aF[i] = *(const short8*)&lA[(wm + i * 16 + c16) * 32 + g4 * 8];
#pragma unroll
        for (int j = 0; j < 4; j++) bF[j] = *(const short8*)&lB[(wn + j * 16 + c16) * 32 + g4 * 8];
#pragma unroll
        for (int i = 0; i < 2; i++)
#pragma unroll
            for (int j = 0; j < 4; j++)
                acc[i][j] = __builtin_amdgcn_mfma_f32_16x16x32_bf16(aF[i], bF[j], acc[i][j], 0, 0, 0);
    }

#pragma unroll
    for (int i = 0; i < 2; i++) {
        int row0 = bm + wm + i * 16 + g4 * 4;
#pragma unroll
        for (int j = 0; j < 4; j++) {
            int col = bn + wn + j * 16 + c16;
            float bv = bias[col];
#pragma unroll
            for (int r = 0; r < 4; r++) {
                int row = row0 + r;
                float v = acc[i][j][r] + bv;
                if (col < scale_ncols) v *= QSCALE;
                if (gelu_flag) v = 0.5f * v * (1.f + erff(v * 0.70710678118654752f));
                if (residual) v += residual[(size_t)row * out_stride + col];
                if (out_f) out_f[(size_t)row * out_stride + col] = v;
                else       out_b[(size_t)row * out_stride + col] = f2b(v);
            }
        }
    }
}

// ---------------- dual GEMM 64x128 (QKV_m for by<ys, KV_c for by>=ys), bf16 out ----------------
__global__ __launch_bounds__(256) void gemm64x128_dual(
    const u16* __restrict__ A0, const u16* __restrict__ B0, const float* __restrict__ bias0,
    u16* __restrict__ out0, int ostride0, int scale0,
    const u16* __restrict__ A1, const u16* __restrict__ B1, const float* __restrict__ bias1,
    u16* __restrict__ out1, int ostride1,
    int ys, int K, int lda, int ldb)
{
    __shared__ u16 lA[64 * 32];
    __shared__ u16 lB[128 * 32];
    int tid = threadIdx.x, wave = tid >> 6, lane = tid & 63;
    int g4 = lane >> 4, c16 = lane & 15;
    int by = blockIdx.y;
    const u16* A; const u16* B; const float* bias; u16* out; int ostride, scaleN, bn;
    if (by < ys) { A = A0; B = B0; bias = bias0; out = out0; ostride = ostride0; scaleN = scale0; bn = by * 128; }
    else         { A = A1; B = B1; bias = bias1; out = out1; ostride = ostride1; scaleN = 0;      bn = (by - ys) * 128; }
    int bm = blockIdx.x * 64;
    int wm = (wave >> 1) * 32, wn = (wave & 1) * 64;
    int srow = tid >> 2, skseg = (tid & 3) * 8;
    const u16* Ar = A + (size_t)(bm + srow) * lda + skseg;
    const u16* Br = B + (size_t)(bn + srow) * ldb + skseg;
    size_t b64o = (size_t)64 * ldb;

    floatx4 acc[2][4];
#pragma unroll
    for (int i = 0; i < 2; i++)
#pragma unroll
        for (int j = 0; j < 4; j++) acc[i][j] = (floatx4){0.f, 0.f, 0.f, 0.f};

    for (int kt = 0; kt < K; kt += 32) {
        __syncthreads();
        gload(Ar + kt,        lA + wave * 512);
        gload(Br + kt,        lB + wave * 512);
        gload(Br + kt + b64o, lB + 2048 + wave * 512);
        __syncthreads();
        short8 aF[2], bF[4];
#pragma unroll
        for (int i = 0; i < 2; i++) aF[i] = *(const short8*)&lA[(wm + i * 16 + c16) * 32 + g4 * 8];
#pragma unroll
        for (int j = 0; j < 4; j++) bF[j] = *(const short8*)&lB[(wn + j * 16 + c16) * 32 + g4 * 8];
#pragma unroll
        for (int i = 0; i < 2; i++)
#pragma unroll
            for (int j = 0; j < 4; j++)
                acc[i][j] = __builtin_amdgcn_mfma_f32_16x16x32_bf16(aF[i], bF[j], acc[i][j], 0, 0, 0);
    }

#pragma unroll
    for (int i = 0; i < 2; i++) {
        int row0 = bm + wm + i * 16 + g4 * 4;
#pragma unroll
        for (int j = 0; j < 4; j++) {
            int col = bn + wn + j * 16 + c16;
            float bv = bias[col];
#pragma unroll
            for (int r = 0; r < 4; r++) {
                float v = acc[i][j][r] + bv;
                if (col < scaleN) v *= QSCALE;
                out[(size_t)(row0 + r) * ostride + col] = f2b(v);
            }
        }
    }
}

// ---------------- GEMM 64x64, bf16/fp32 out, single-pass (used for Q_c) ----------------
__global__ __launch_bounds__(256) void gemm64x64(
    const u16* __restrict__ A, int lda,
    const u16* __restrict__ B, int ldb,
    int K,
    const float* __restrict__ bias,
    float* __restrict__ out_f, u16* __restrict__ out_b,
    int out_stride, int scale_ncols)
{
    __shared__ u16 lA[64 * 32];
    __shared__ u16 lB[64 * 32];
    int tid = threadIdx.x, wave = tid >> 6, lane = tid & 63;
    int g4 = lane >> 4, c16 = lane & 15;
    int bm = blockIdx.x * 64, bn = blockIdx.y * 64;
    int wm = wave * 16;
    int srow = tid >> 2, skseg = (tid & 3) * 8;
    const u16* Ar = A + (size_t)(bm + srow) * lda + skseg;
    const u16* Br = B + (size_t)(bn + srow) * ldb + skseg;

    floatx4 acc[4];
#pragma unroll
    for (int j = 0; j < 4; j++) acc[j] = (floatx4){0.f, 0.f, 0.f, 0.f};

    for (int kt = 0; kt < K; kt += 32) {
        __syncthreads();
        gload(Ar + kt, lA + wave * 512);
        gload(Br + kt, lB + wave * 512);
        __syncthreads();
        short8 aF = *(const short8*)&lA[(wm + c16) * 32 + g4 * 8];
        short8 bF[4];
#pragma unroll
        for (int j = 0; j < 4; j++) bF[j] = *(const short8*)&lB[(j * 16 + c16) * 32 + g4 * 8];
#pragma unroll
        for (int j = 0; j < 4; j++)
            acc[j] = __builtin_amdgcn_mfma_f32_16x16x32_bf16(aF, bF[j], acc[j], 0, 0, 0);
    }

    int row0 = bm + wm + g4 * 4;
#pragma unroll
    for (int j = 0; j < 4; j++) {
        int col = bn + j * 16 + c16;
        float bv = bias[col];
#pragma unroll
        for (int r = 0; r < 4; r++) {
            int row = row0 + r;
            float v = acc[j][r] + bv;
            if (col < scale_ncols) v *= QSCALE;
            if (out_f) out_f[(size_t)row * out_stride + col] = v;
            else       out_b[(size_t)row * out_stride + col] = f2b(v);
        }
    }
}

// ---------------- GEMM 64x64 K-split-2: fp32 partials. grid (M/64, N/64, 2) ----------------
// sp==0 adds bias + residual (fp32 OR bf16 source). Consumer (LN) adds the two slabs.
__global__ __launch_bounds__(256) void gemm64x64s(
    const u16* __restrict__ A, int lda,
    const u16* __restrict__ B, int ldb,
    int Ksub,
    const float* __restrict__ bias,
    const float* __restrict__ res_f,
    const u16* __restrict__ res_b,
    float* __restrict__ out0, int out_stride)
{
    __shared__ u16 lA[64 * 32];
    __shared__ u16 lB[64 * 32];
    int tid = threadIdx.x, wave = tid >> 6, lane = tid & 63;
    int g4 = lane >> 4, c16 = lane & 15;
    int bm = blockIdx.x * 64, bn = blockIdx.y * 64, sp = blockIdx.z;
    int wm = wave * 16;
    int srow = tid >> 2, skseg = (tid & 3) * 8 + sp * Ksub;
    const u16* Ar = A + (size_t)(bm + srow) * lda + skseg;
    const u16* Br = B + (size_t)(bn + srow) * ldb + skseg;

    floatx4 acc[4];
#pragma unroll
    for (int j = 0; j < 4; j++) acc[j] = (floatx4){0.f, 0.f, 0.f, 0.f};

    for (int kt = 0; kt < Ksub; kt += 32) {
        __syncthreads();
        gload(Ar + kt, lA + wave * 512);
        gload(Br + kt, lB + wave * 512);
        __syncthreads();
        short8 aF = *(const short8*)&lA[(wm + c16) * 32 + g4 * 8];
        short8 bF[4];
#pragma unroll
        for (int j = 0; j < 4; j++) bF[j] = *(const short8*)&lB[(j * 16 + c16) * 32 + g4 * 8];
#pragma unroll
        for (int j = 0; j < 4; j++)
            acc[j] = __builtin_amdgcn_mfma_f32_16x16x32_bf16(aF, bF[j], acc[j], 0, 0, 0);
    }

    float* out = out0 + (size_t)sp * 4096 * 512;
    int row0 = bm + wm + g4 * 4;
#pragma unroll
    for (int j = 0; j < 4; j++) {
        int col = bn + j * 16 + c16;
        float bv = (sp == 0) ? bias[col] : 0.f;
#pragma unroll
        for (int r = 0; r < 4; r++) {
            int row = row0 + r;
            float v = acc[j][r] + bv;
            if (sp == 0) {
                if (res_f)      v += res_f[(size_t)row * out_stride + col];
                else if (res_b) v += b2f(res_b[(size_t)row * out_stride + col]);
            }
            out[(size_t)row * out_stride + col] = v;
        }
    }
}

// ---------------- flash attention: 64-row Q-tile, 2-way key split, causal big-first -------
// grid (32 q-tiles, B*H, 2 splits), block 256. Split s: tiles {s, s+2, ...}.
// Causal: qt = 31 - blockIdx.x so heaviest blocks dispatch first (load balance).
// No max-subtraction -> partials combine exactly. bf16 unnormalized O partials + fp32 row sums.
__global__ __launch_bounds__(256) void attn_fused(
    const u16* __restrict__ Qp, int q_stride,
    const u16* __restrict__ Kp, int kv_stride,
    const u16* __restrict__ Vp,
    u16* __restrict__ Opart,     // [2][16][2048][64] bf16
    float* __restrict__ Lpart,   // [2][16][2048]
    int causal)
{
    __shared__ u16 lK[64 * 72];    // [key][dh]
    __shared__ u16 lVT[64 * 72];   // [dh][key^swz]
    __shared__ u16 lP[4 * 16 * 72];// per-wave private [qrow][key]
    int tid = threadIdx.x, wave = tid >> 6, lane = tid & 63;
    int g4 = lane >> 4, c16 = lane & 15;
    int qt = causal ? (31 - blockIdx.x) : blockIdx.x;
    int bh = blockIdx.y, sp = blockIdx.z;
    size_t rowbase = (size_t)(bh >> 3) * 2048;
    int hoff = (bh & 7) * 64;
    const u16* Q = Qp + rowbase * q_stride + hoff;
    const u16* K = Kp + rowbase * kv_stride + hoff;
    const u16* V = Vp + rowbase * kv_stride + hoff;

    int qrow0 = qt * 64 + wave * 16;
    short8 qf0 = *(const short8*)&Q[(size_t)(qrow0 + c16) * q_stride + g4 * 8];
    short8 qf1 = *(const short8*)&Q[(size_t)(qrow0 + c16) * q_stride + g4 * 8 + 32];

    // staging addresses
    int kr = tid >> 2, ks = (tid & 3) * 16;                 // K: row, u16 col offset
    const u16* Kbase = K + (size_t)kr * kv_stride + ks;
    int vk0 = (tid >> 3) * 2, vs = (tid & 7) * 8;           // V: key pair, dh offset
    const u16* Vbase = V + (size_t)vk0 * kv_stride + vs;

    int4 kv0, kv1, vv0, vv1;
    auto load_tile = [&](int kt) {
        const u16* kp = Kbase + (size_t)kt * 64 * kv_stride;
        kv0 = *(const int4*)(kp);
        kv1 = *(const int4*)(kp + 8);
        const u16* vp = Vbase + (size_t)kt * 64 * kv_stride;
        vv0 = *(const int4*)(vp);
        vv1 = *(const int4*)(vp + kv_stride);
    };
    auto store_tile = [&]() {
        *(int4*)&lK[kr * 72 + ks] = kv0;
        *(int4*)&lK[kr * 72 + ks + 8] = kv1;
        const u16* pa = (const u16*)&vv0;
        const u16* pb = (const u16*)&vv1;
#pragma unroll
        for (int j = 0; j < 8; j++) {
            int dh = vs + j;
            int keyS = vk0 ^ (((dh >> 3) & 3) << 4);       // XOR swizzle kills 8-way bank conflict
            u32 w = (u32)pa[j] | ((u32)pb[j] << 16);
            *(u32*)&lVT[dh * 72 + keyS] = w;
        }
    };

    floatx4 o_acc[4];
#pragma unroll
    for (int d = 0; d < 4; d++) o_acc[d] = (floatx4){0.f, 0.f, 0.f, 0.f};
    float lsum = 0.f;                                       // row sum for qrow = c16
    u16* lPw = lP + wave * 1152;

    int ktend = causal ? (qt + 1) : 32;
    int kt = sp;
    if (kt < ktend) load_tile(kt);

    for (; kt < ktend; kt += 2) {
        __syncthreads();           // prior tile's LDS reads complete
        store_tile();
        __syncthreads();           // staging visible
        if (kt + 2 < ktend) load_tile(kt + 2);   // prefetch overlaps compute

        // S^T = K Q^T : lane holds qrow=c16, keys nt*16 + 4*g4 + r (key-contiguous)
        floatx4 sc[4];
#pragma unroll
        for (int nt = 0; nt < 4; nt++) {
            short8 b0 = *(const short8*)&lK[(nt * 16 + c16) * 72 + g4 * 8];
            short8 b1 = *(const short8*)&lK[(nt * 16 + c16) * 72 + g4 * 8 + 32];
            floatx4 z = (floatx4){0.f, 0.f, 0.f, 0.f};
            z = __builtin_amdgcn_mfma_f32_16x16x32_bf16(b0, qf0, z, 0, 0, 0);
            z = __builtin_amdgcn_mfma_f32_16x16x32_bf16(b1, qf1, z, 0, 0, 0);
            sc[nt] = z;
        }
        if (causal && kt == qt) {
            int qr = qt * 64 + wave * 16 + c16;
#pragma unroll
            for (int nt = 0; nt < 4; nt++) {
                int key0 = kt * 64 + nt * 16 + 4 * g4;
#pragma unroll
                for (int r = 0; r < 4; r++)
                    if (key0 + r > qr) sc[nt][r] = -1e30f;
            }
        }
        // P = exp2(S); per-lane row sum; b64 writes to per-wave lP (no barrier)
#pragma unroll
        for (int nt = 0; nt < 4; nt++) {
            float p0 = exp2f(sc[nt][0]);
            float p1 = exp2f(sc[nt][1]);
            float p2 = exp2f(sc[nt][2]);
            float p3 = exp2f(sc[nt][3]);
            lsum += (p0 + p1) + (p2 + p3);
            __hip_bfloat162 w0 = __float22bfloat162_rn(make_float2(p0, p1));
            __hip_bfloat162 w1 = __float22bfloat162_rn(make_float2(p2, p3));
            uint2 pk; pk.x = *(u32*)&w0; pk.y = *(u32*)&w1;
            *(uint2*)&lPw[c16 * 72 + nt * 16 + 4 * g4] = pk;
        }
        // O += P V
        short8 pa0 = *(const short8*)&lPw[c16 * 72 + g4 * 8];
        short8 pa1 = *(const short8*)&lPw[c16 * 72 + g4 * 8 + 32];
#pragma unroll
        for (int d = 0; d < 4; d++) {
            int swz = ((2 * d + (c16 >> 3)) & 3) << 4;
            short8 vb0 = *(const short8*)&lVT[(d * 16 + c16) * 72 + ((g4 * 8) ^ swz)];
            short8 vb1 = *(const short8*)&lVT[(d * 16 + c16) * 72 + ((32 + g4 * 8) ^ swz)];
            o_acc[d] = __builtin_amdgcn_mfma_f32_16x16x32_bf16(pa0, vb0, o_acc[d], 0, 0, 0);
            o_acc[d] = __builtin_amdgcn_mfma_f32_16x16x32_bf16(pa1, vb1, o_acc[d], 0, 0, 0);
        }
    }

    // reduce lsum across the 4 lanes sharing qrow=c16; store partial sum + unnormalized bf16 O
    lsum += __shfl_xor(lsum, 16);
    lsum += __shfl_xor(lsum, 32);
    size_t slab = (size_t)(sp * 16 + bh) * 2048;
    if (g4 == 0) Lpart[slab + qrow0 + c16] = lsum;
    u16* Ob = Opart + (slab + qrow0) * 64;
#pragma unroll
    for (int d = 0; d < 4; d++)
#pragma unroll
        for (int r = 0; r < 4; r++)
            Ob[(size_t)(4 * g4 + r) * 64 + d * 16 + c16] = f2b(o_acc[d][r]);
}

// ---------------- combine 2 bf16 split partials -> bf16 [4096][512] ----------------
__global__ __launch_bounds__(256) void attn_combine(
    const ushort4* __restrict__ Op,  // [2][16][2048][16 ushort4]
    const float* __restrict__ Lp,    // [2][16][2048]
    ushort4* __restrict__ out)       // [4096][128 ushort4]
{
    int e = blockIdx.x * 256 + threadIdx.x;        // 0 .. 524287
    int dh4 = e & 15;
    int qrow = (e >> 4) & 2047;
    int bh = e >> 15;
    int li = bh * 2048 + qrow;
    float l = Lp[li] + Lp[32768 + li];
    float inv = 1.f / l;
    ushort4 a = Op[e];
    ushort4 b = Op[524288 + e];
    ushort4 o;
    o.x = f2b((b2f(a.x) + b2f(b.x)) * inv);
    o.y = f2b((b2f(a.y) + b2f(b.y)) * inv);
    o.z = f2b((b2f(a.z) + b2f(b.z)) * inv);
    o.w = f2b((b2f(a.w) + b2f(b.w)) * inv);
    int row = (bh >> 3) * 2048 + qrow;
    out[(size_t)row * 128 + (bh & 7) * 16 + dh4] = o;
}

// ---------------- LayerNorm (row=512), in = in0 (+ in1), emits fp32 and/or bf16 -------
__global__ __launch_bounds__(256) void ln_kernel(const float* __restrict__ in0,
                                                 const float* __restrict__ in1,
                                                 const float* __restrict__ g,
                                                 const float* __restrict__ b,
                                                 float* __restrict__ out_f,
                                                 u16* __restrict__ out_b)
{
    const int D = 512;
    int row = blockIdx.x, tid = threadIdx.x;
    size_t base = (size_t)row * D;
    float v0 = in0[base + tid], v1 = in0[base + tid + 256];
    if (in1) { v0 += in1[base + tid]; v1 += in1[base + tid + 256]; }
    float s = v0 + v1, ss = v0 * v0 + v1 * v1;
#pragma unroll
    for (int off = 1; off < 64; off <<= 1) { s += __shfl_xor(s, off); ss += __shfl_xor(ss, off); }
    __shared__ float red[8];
    int wave = tid >> 6, lane = tid & 63;
    if (lane == 0) { red[wave] = s; red[4 + wave] = ss; }
    __syncthreads();
    float st = red[0] + red[1] + red[2] + red[3];
    float sst = red[4] + red[5] + red[6] + red[7];
    float mu = st * (1.f / 512.f);
    float var = sst * (1.f / 512.f) - mu * mu;
    float rs = rsqrtf(var + 1e-5f);
    float y0 = (v0 - mu) * rs * g[tid] + b[tid];
    float y1 = (v1 - mu) * rs * g[tid + 256] + b[tid + 256];
    if (out_f) { out_f[base + tid] = y0; out_f[base + tid + 256] = y1; }
    if (out_b) { out_b[base + tid] = f2b(y0); out_b[base + tid + 256] = f2b(y1); }
}

// ---------------- launch ----------------
extern "C" void kernel_launch(void* const* d_in, const int* in_sizes, int n_in,
                              void* d_out, int out_size, void* d_ws, size_t ws_size,
                              hipStream_t stream)
{
    (void)in_sizes; (void)n_in; (void)out_size; (void)ws_size;
    const float* x     = (const float*)d_in[0];
    const float* enc   = (const float*)d_in[1];
    const float* m_wq  = (const float*)d_in[2];  const float* m_bq = (const float*)d_in[3];
    const float* m_wk  = (const float*)d_in[4];  const float* m_bk = (const float*)d_in[5];
    const float* m_wv  = (const float*)d_in[6];  const float* m_bv = (const float*)d_in[7];
    const float* m_wo  = (const float*)d_in[8];  const float* m_bo = (const float*)d_in[9];
    const float* c_wq  = (const float*)d_in[10]; const float* c_bq = (const float*)d_in[11];
    const float* c_wk  = (const float*)d_in[12]; const float* c_bk = (const float*)d_in[13];
    const float* c_wv  = (const float*)d_in[14]; const float* c_bv = (const float*)d_in[15];
    const float* c_wo  = (const float*)d_in[16]; const float* c_bo = (const float*)d_in[17];
    const float* ln1_g = (const float*)d_in[18]; const float* ln1_b = (const float*)d_in[19];
    const float* ln2_g = (const float*)d_in[20]; const float* ln2_b = (const float*)d_in[21];
    const float* ln3_g = (const float*)d_in[22]; const float* ln3_b = (const float*)d_in[23];
    const float* ff_w1 = (const float*)d_in[24]; const float* ff_b1 = (const float*)d_in[25];
    const float* ff_w2 = (const float*)d_in[26]; const float* ff_b2 = (const float*)d_in[27];

    char* base = (char*)d_ws; size_t off = 0;
    auto alloc = [&](size_t bytes) -> void* {
        void* p = base + off; off = (off + bytes + 255) & ~(size_t)255; return p;
    };
    u16*   Wqkv_m = (u16*)alloc(1536 * 512 * 2);
    u16*   Wo_m   = (u16*)alloc(512 * 512 * 2);
    u16*   Wq_c   = (u16*)alloc(512 * 512 * 2);
    u16*   Wkv_c  = (u16*)alloc(1024 * 512 * 2);
    u16*   Wo_c   = (u16*)alloc(512 * 512 * 2);
    u16*   W1t    = (u16*)alloc(2048 * 512 * 2);
    u16*   W2t    = (u16*)alloc(512 * 2048 * 2);
    float* bqkv_m = (float*)alloc(1536 * 4);
    float* bkv_c  = (float*)alloc(1024 * 4);
    u16*   xb     = (u16*)alloc((size_t)4096 * 512 * 2);
    u16*   encb   = (u16*)alloc((size_t)4096 * 512 * 2);
    u16*   qkvm   = (u16*)alloc((size_t)4096 * 1536 * 2);
    u16*   attnm  = (u16*)alloc((size_t)4096 * 512 * 2);
    float* y01    = (float*)alloc((size_t)2 * 4096 * 512 * 4);   // K-split partials
    u16*   x1b    = (u16*)alloc((size_t)4096 * 512 * 2);
    u16*   qc     = (u16*)alloc((size_t)4096 * 512 * 2);
    u16*   kvc    = (u16*)alloc((size_t)4096 * 1024 * 2);
    u16*   attnc  = (u16*)alloc((size_t)4096 * 512 * 2);
    u16*   x2b    = (u16*)alloc((size_t)4096 * 512 * 2);
    u16*   h      = (u16*)alloc((size_t)4096 * 2048 * 2);
    u16*   Opart  = (u16*)alloc((size_t)2 * 16 * 2048 * 64 * 2);
    float* Lpart  = (float*)alloc((size_t)2 * 16 * 2048 * 4);

    // ---- preprocessing: 3 launches ----
    TP16 tp;
    tp.e[0] = {m_wq, Wqkv_m,              512, 512};
    tp.e[1] = {m_wk, Wqkv_m + 512 * 512,  512, 512};
    tp.e[2] = {m_wv, Wqkv_m + 1024 * 512, 512, 512};
    tp.e[3] = {m_wo, Wo_m,                512, 512};
    tp.e[4] = {c_wq, Wq_c,                512, 512};
    tp.e[5] = {c_wk, Wkv_c,               512, 512};
    tp.e[6] = {c_wv, Wkv_c + 512 * 512,   512, 512};
    tp.e[7] = {c_wo, Wo_c,                512, 512};
    for (int k = 0; k < 4; k++)
        tp.e[8 + k]  = {ff_w1 + 512 * k,        W1t + k * 512 * 512, 2048, 512};
    for (int k = 0; k < 4; k++)
        tp.e[12 + k] = {ff_w2 + (size_t)512 * k * 512, W2t + 512 * k, 512, 2048};
    transpose_convert16<<<dim3(16, 16, 16), dim3(32, 8), 0, stream>>>(tp);
    gather_bias<<<10, 256, 0, stream>>>(m_bq, m_bk, m_bv, c_bk, c_bv, bqkv_m, bkv_c);
    cvt_bf16_2<<<2048, 256, 0, stream>>>((const float4*)x, (ushort4*)xb,
                                         (const float4*)enc, (ushort4*)encb);

    // ---- fused QKV_m + KV_c projections (KV_c has no upstream deps) ----
    gemm64x128_dual<<<dim3(64, 20), 256, 0, stream>>>(
        xb, Wqkv_m, bqkv_m, qkvm, 1536, 512,
        encb, Wkv_c, bkv_c, kvc, 1024,
        12, 512, 512, 512);

    // ---- self attention block ----
    attn_fused<<<dim3(32, 16, 2), 256, 0, stream>>>(qkvm, 1536, qkvm + 512, 1536, qkvm + 1024,
                                                    Opart, Lpart, 1);
    attn_combine<<<2048, 256, 0, stream>>>((const ushort4*)Opart, Lpart, (ushort4*)attnm);
    gemm64x64s<<<dim3(64, 8, 2), 256, 0, stream>>>(attnm, 512, Wo_m, 512, 256,
                                                   m_bo, x, nullptr, y01, 512);
    ln_kernel<<<4096, 256, 0, stream>>>(y01, y01 + (size_t)4096 * 512, ln1_g, ln1_b,
                                        nullptr, x1b);

    // ---- cross attention block ----
    gemm64x64<<<dim3(64, 8), 256, 0, stream>>>(x1b, 512, Wq_c, 512, 512,
                                               c_bq, nullptr, qc, 512, 512);
    attn_fused<<<dim3(32, 16, 2), 256, 0, stream>>>(qc, 512, kvc, 1024, kvc + 512,
                                                    Opart, Lpart, 0);
    attn_combine<<<2048, 256, 0, stream>>>((const ushort4*)Opart, Lpart, (ushort4*)attnc);
    gemm64x64s<<<dim3(64, 8, 2), 256, 0, stream>>>(attnc, 512, Wo_c, 512, 256,
                                                   c_bo, nullptr, x1b, y01, 512);
    ln_kernel<<<4096, 256, 0, stream>>>(y01, y01 + (size_t)4096 * 512, ln2_g, ln2_b,
                                        nullptr, x2b);

    // ---- feed forward ----
    gemm64x128<<<dim3(64, 16), 256, 0, stream>>>(x2b, 512, W1t, 512, 512,
                                                 ff_b1, nullptr, nullptr, h, 2048, 0, 1);
    gemm64x64s<<<dim3(64, 8, 2), 256, 0, stream>>>(h, 2048, W2t, 2048, 1024,
                                                   ff_b2, nullptr, x2b, y01, 512);
    ln_kernel<<<4096, 256, 0, stream>>>(y01, y01 + (size_t)4096 * 512, ln3_g, ln3_b,
                                        (float*)d_out, nullptr);
}

// Round 10
// 320.885 us; speedup vs baseline: 1.2372x; 1.0411x over previous
//
#include <hip/hip_runtime.h>
#include <hip/hip_bf16.h>

typedef __attribute__((ext_vector_type(8))) short short8;
typedef __attribute__((ext_vector_type(4))) float floatx4;
typedef unsigned short u16;
typedef unsigned int u32;

#define QSCALE 0.1803368801111244f   // 0.125 * log2(e): folded into Q so softmax is exp2(S)

__device__ __forceinline__ u16 f2b(float f) {
    union { float f; u32 u; } v; v.f = f;
    u32 r = v.u + 0x7fffu + ((v.u >> 16) & 1u);   // RNE
    return (u16)(r >> 16);
}

__device__ __forceinline__ float b2f(u16 b) {
    u32 u = ((u32)b) << 16;
    union { u32 u; float f; } v; v.u = u;
    return v.f;
}

__device__ __forceinline__ void gload(const u16* g, u16* l) {
    __builtin_amdgcn_global_load_lds((const __attribute__((address_space(1))) void*)g,
                                     (__attribute__((address_space(3))) void*)l, 16, 0, 0);
}

// ---------------- batched weight transpose + fp32->bf16 (16 x 512x512 tiles) ----------------
struct TPent { const float* s; u16* d; int O; int dI; };
struct TP16 { TPent e[16]; };
__global__ __launch_bounds__(256) void transpose_convert16(TP16 p) {
    __shared__ float t[32][33];
    TPent e = p.e[blockIdx.z];
    int o0 = blockIdx.x * 32, i0 = blockIdx.y * 32;
    int tx = threadIdx.x, ty = threadIdx.y;
#pragma unroll
    for (int k = 0; k < 32; k += 8) t[ty + k][tx] = e.s[(size_t)(i0 + ty + k) * e.O + o0 + tx];
    __syncthreads();
#pragma unroll
    for (int k = 0; k < 32; k += 8) e.d[(size_t)(o0 + ty + k) * e.dI + i0 + tx] = f2b(t[tx][ty + k]);
}

// gather 5 bias vectors into 2 concat buffers. grid 10 x 256
__global__ __launch_bounds__(256) void gather_bias(const float* b0, const float* b1, const float* b2,
                                                   const float* b3, const float* b4,
                                                   float* dqkv, float* dkv) {
    int i = blockIdx.x * 256 + threadIdx.x;
    if      (i < 512)  dqkv[i] = b0[i];
    else if (i < 1024) dqkv[i] = b1[i - 512];
    else if (i < 1536) dqkv[i] = b2[i - 1024];
    else if (i < 2048) dkv[i - 1536] = b3[i - 1536];
    else               dkv[i - 1536] = b4[i - 2048];
}

// fp32 -> bf16 for x and enc in one launch. grid 2048 x 256, 4 elems each.
__global__ __launch_bounds__(256) void cvt_bf16_2(const float4* __restrict__ s0, ushort4* __restrict__ d0,
                                                  const float4* __restrict__ s1, ushort4* __restrict__ d1) {
    int i = blockIdx.x * 256 + threadIdx.x;
    float4 v = s0[i];
    ushort4 o; o.x = f2b(v.x); o.y = f2b(v.y); o.z = f2b(v.z); o.w = f2b(v.w);
    d0[i] = o;
    v = s1[i];
    o.x = f2b(v.x); o.y = f2b(v.y); o.z = f2b(v.z); o.w = f2b(v.w);
    d1[i] = o;
}

// ---------------- GEMM 64x128: C = A[M,K] @ Bt[N,K] + epilogue. grid (M/64, N/128) ----------------
__global__ __launch_bounds__(256) void gemm64x128(
    const u16* __restrict__ A, int lda,
    const u16* __restrict__ B, int ldb,
    int K,
    const float* __restrict__ bias,
    const float* __restrict__ residual,
    float* __restrict__ out_f, u16* __restrict__ out_b,
    int out_stride, int scale_ncols, int gelu_flag)
{
    __shared__ u16 lA[64 * 32];
    __shared__ u16 lB[128 * 32];
    int tid = threadIdx.x, wave = tid >> 6, lane = tid & 63;
    int g4 = lane >> 4, c16 = lane & 15;
    int bm = blockIdx.x * 64, bn = blockIdx.y * 128;
    int wm = (wave >> 1) * 32, wn = (wave & 1) * 64;
    int srow = tid >> 2, skseg = (tid & 3) * 8;
    const u16* Ar = A + (size_t)(bm + srow) * lda + skseg;
    const u16* Br = B + (size_t)(bn + srow) * ldb + skseg;
    size_t b64o = (size_t)64 * ldb;

    floatx4 acc[2][4];
#pragma unroll
    for (int i = 0; i < 2; i++)
#pragma unroll
        for (int j = 0; j < 4; j++) acc[i][j] = (floatx4){0.f, 0.f, 0.f, 0.f};

    for (int kt = 0; kt < K; kt += 32) {
        __syncthreads();
        gload(Ar + kt,        lA + wave * 512);
        gload(Br + kt,        lB + wave * 512);
        gload(Br + kt + b64o, lB + 2048 + wave * 512);
        __syncthreads();
        short8 aF[2], bF[4];
#pragma unroll
        for (int i = 0; i < 2; i++) aF[i] = *(const short8*)&lA[(wm + i * 16 + c16) * 32 + g4 * 8];
#pragma unroll
        for (int j = 0; j < 4; j++) bF[j] = *(const short8*)&lB[(wn + j * 16 + c16) * 32 + g4 * 8];
#pragma unroll
        for (int i = 0; i < 2; i++)
#pragma unroll
            for (int j = 0; j < 4; j++)
                acc[i][j] = __builtin_amdgcn_mfma_f32_16x16x32_bf16(aF[i], bF[j], acc[i][j], 0, 0, 0);
    }

#pragma unroll
    for (int i = 0; i < 2; i++) {
        int row0 = bm + wm + i * 16 + g4 * 4;
#pragma unroll
        for (int j = 0; j < 4; j++) {
            int col = bn + wn + j * 16 + c16;
            float bv = bias[col];
#pragma unroll
            for (int r = 0; r < 4; r++) {
                int row = row0 + r;
                float v = acc[i][j][r] + bv;
                if (col < scale_ncols) v *= QSCALE;
                if (gelu_flag) v = 0.5f * v * (1.f + erff(v * 0.70710678118654752f));
                if (residual) v += residual[(size_t)row * out_stride + col];
                if (out_f) out_f[(size_t)row * out_stride + col] = v;
                else       out_b[(size_t)row * out_stride + col] = f2b(v);
            }
        }
    }
}

// ---------------- dual GEMM 64x128 (QKV_m for by<ys, KV_c for by>=ys), bf16 out ----------------
__global__ __launch_bounds__(256) void gemm64x128_dual(
    const u16* __restrict__ A0, const u16* __restrict__ B0, const float* __restrict__ bias0,
    u16* __restrict__ out0, int ostride0, int scale0,
    const u16* __restrict__ A1, const u16* __restrict__ B1, const float* __restrict__ bias1,
    u16* __restrict__ out1, int ostride1,
    int ys, int K, int lda, int ldb)
{
    __shared__ u16 lA[64 * 32];
    __shared__ u16 lB[128 * 32];
    int tid = threadIdx.x, wave = tid >> 6, lane = tid & 63;
    int g4 = lane >> 4, c16 = lane & 15;
    int by = blockIdx.y;
    const u16* A; const u16* B; const float* bias; u16* out; int ostride, scaleN, bn;
    if (by < ys) { A = A0; B = B0; bias = bias0; out = out0; ostride = ostride0; scaleN = scale0; bn = by * 128; }
    else         { A = A1; B = B1; bias = bias1; out = out1; ostride = ostride1; scaleN = 0;      bn = (by - ys) * 128; }
    int bm = blockIdx.x * 64;
    int wm = (wave >> 1) * 32, wn = (wave & 1) * 64;
    int srow = tid >> 2, skseg = (tid & 3) * 8;
    const u16* Ar = A + (size_t)(bm + srow) * lda + skseg;
    const u16* Br = B + (size_t)(bn + srow) * ldb + skseg;
    size_t b64o = (size_t)64 * ldb;

    floatx4 acc[2][4];
#pragma unroll
    for (int i = 0; i < 2; i++)
#pragma unroll
        for (int j = 0; j < 4; j++) acc[i][j] = (floatx4){0.f, 0.f, 0.f, 0.f};

    for (int kt = 0; kt < K; kt += 32) {
        __syncthreads();
        gload(Ar + kt,        lA + wave * 512);
        gload(Br + kt,        lB + wave * 512);
        gload(Br + kt + b64o, lB + 2048 + wave * 512);
        __syncthreads();
        short8 aF[2], bF[4];
#pragma unroll
        for (int i = 0; i < 2; i++) aF[i] = *(const short8*)&lA[(wm + i * 16 + c16) * 32 + g4 * 8];
#pragma unroll
        for (int j = 0; j < 4; j++) bF[j] = *(const short8*)&lB[(wn + j * 16 + c16) * 32 + g4 * 8];
#pragma unroll
        for (int i = 0; i < 2; i++)
#pragma unroll
            for (int j = 0; j < 4; j++)
                acc[i][j] = __builtin_amdgcn_mfma_f32_16x16x32_bf16(aF[i], bF[j], acc[i][j], 0, 0, 0);
    }

#pragma unroll
    for (int i = 0; i < 2; i++) {
        int row0 = bm + wm + i * 16 + g4 * 4;
#pragma unroll
        for (int j = 0; j < 4; j++) {
            int col = bn + wn + j * 16 + c16;
            float bv = bias[col];
#pragma unroll
            for (int r = 0; r < 4; r++) {
                float v = acc[i][j][r] + bv;
                if (col < scaleN) v *= QSCALE;
                out[(size_t)(row0 + r) * ostride + col] = f2b(v);
            }
        }
    }
}

// ---------------- GEMM 64x64, bf16 out, single-pass (used for Q_c) ----------------
__global__ __launch_bounds__(256) void gemm64x64(
    const u16* __restrict__ A, int lda,
    const u16* __restrict__ B, int ldb,
    int K,
    const float* __restrict__ bias,
    u16* __restrict__ out_b,
    int out_stride, int scale_ncols)
{
    __shared__ u16 lA[64 * 32];
    __shared__ u16 lB[64 * 32];
    int tid = threadIdx.x, wave = tid >> 6, lane = tid & 63;
    int g4 = lane >> 4, c16 = lane & 15;
    int bm = blockIdx.x * 64, bn = blockIdx.y * 64;
    int wm = wave * 16;
    int srow = tid >> 2, skseg = (tid & 3) * 8;
    const u16* Ar = A + (size_t)(bm + srow) * lda + skseg;
    const u16* Br = B + (size_t)(bn + srow) * ldb + skseg;

    floatx4 acc[4];
#pragma unroll
    for (int j = 0; j < 4; j++) acc[j] = (floatx4){0.f, 0.f, 0.f, 0.f};

    for (int kt = 0; kt < K; kt += 32) {
        __syncthreads();
        gload(Ar + kt, lA + wave * 512);
        gload(Br + kt, lB + wave * 512);
        __syncthreads();
        short8 aF = *(const short8*)&lA[(wm + c16) * 32 + g4 * 8];
        short8 bF[4];
#pragma unroll
        for (int j = 0; j < 4; j++) bF[j] = *(const short8*)&lB[(j * 16 + c16) * 32 + g4 * 8];
#pragma unroll
        for (int j = 0; j < 4; j++)
            acc[j] = __builtin_amdgcn_mfma_f32_16x16x32_bf16(aF, bF[j], acc[j], 0, 0, 0);
    }

    int row0 = bm + wm + g4 * 4;
#pragma unroll
    for (int j = 0; j < 4; j++) {
        int col = bn + j * 16 + c16;
        float bv = bias[col];
#pragma unroll
        for (int r = 0; r < 4; r++) {
            int row = row0 + r;
            float v = acc[j][r] + bv;
            if (col < scale_ncols) v *= QSCALE;
            out_b[(size_t)row * out_stride + col] = f2b(v);
        }
    }
}

// ---------------- GEMM 64x64 K-split-2: bf16 partials. grid (M/64, N/64, 2) ----------------
// sp==0 adds bias + residual (fp32 OR bf16 source). Consumer (LN) adds the two bf16 slabs.
__global__ __launch_bounds__(256) void gemm64x64s(
    const u16* __restrict__ A, int lda,
    const u16* __restrict__ B, int ldb,
    int Ksub,
    const float* __restrict__ bias,
    const float* __restrict__ res_f,
    const u16* __restrict__ res_b,
    u16* __restrict__ out0, int out_stride)
{
    __shared__ u16 lA[64 * 32];
    __shared__ u16 lB[64 * 32];
    int tid = threadIdx.x, wave = tid >> 6, lane = tid & 63;
    int g4 = lane >> 4, c16 = lane & 15;
    int bm = blockIdx.x * 64, bn = blockIdx.y * 64, sp = blockIdx.z;
    int wm = wave * 16;
    int srow = tid >> 2, skseg = (tid & 3) * 8 + sp * Ksub;
    const u16* Ar = A + (size_t)(bm + srow) * lda + skseg;
    const u16* Br = B + (size_t)(bn + srow) * ldb + skseg;

    floatx4 acc[4];
#pragma unroll
    for (int j = 0; j < 4; j++) acc[j] = (floatx4){0.f, 0.f, 0.f, 0.f};

    for (int kt = 0; kt < Ksub; kt += 32) {
        __syncthreads();
        gload(Ar + kt, lA + wave * 512);
        gload(Br + kt, lB + wave * 512);
        __syncthreads();
        short8 aF = *(const short8*)&lA[(wm + c16) * 32 + g4 * 8];
        short8 bF[4];
#pragma unroll
        for (int j = 0; j < 4; j++) bF[j] = *(const short8*)&lB[(j * 16 + c16) * 32 + g4 * 8];
#pragma unroll
        for (int j = 0; j < 4; j++)
            acc[j] = __builtin_amdgcn_mfma_f32_16x16x32_bf16(aF, bF[j], acc[j], 0, 0, 0);
    }

    u16* out = out0 + (size_t)sp * 4096 * 512;
    int row0 = bm + wm + g4 * 4;
#pragma unroll
    for (int j = 0; j < 4; j++) {
        int col = bn + j * 16 + c16;
        float bv = (sp == 0) ? bias[col] : 0.f;
#pragma unroll
        for (int r = 0; r < 4; r++) {
            int row = row0 + r;
            float v = acc[j][r] + bv;
            if (sp == 0) {
                if (res_f)      v += res_f[(size_t)row * out_stride + col];
                else if (res_b) v += b2f(res_b[(size_t)row * out_stride + col]);
            }
            out[(size_t)row * out_stride + col] = f2b(v);
        }
    }
}

// ---------------- flash attention: XCD-swizzled, 64-row Q-tile, 2-way key split -------
// grid 1024 (flattened), block 256. Decode maps bh&7 == dispatch_id&7 so each XCD's L2
// caches only 2 heads' KV (1 MB). Split s: tiles {s, s+2, ...}.
// No max-subtraction -> partials combine exactly. bf16 unnormalized O partials + fp32 row sums.
__global__ __launch_bounds__(256) void attn_fused(
    const u16* __restrict__ Qp, int q_stride,
    const u16* __restrict__ Kp, int kv_stride,
    const u16* __restrict__ Vp,
    u16* __restrict__ Opart,     // [2][16][2048][64] bf16
    float* __restrict__ Lpart,   // [2][16][2048]
    int causal)
{
    __shared__ u16 lK[64 * 72];    // [key][dh]
    __shared__ u16 lVT[64 * 72];   // [dh][key^swz]
    __shared__ u16 lP[4 * 16 * 72];// per-wave private [qrow][key]
    int tid = threadIdx.x, wave = tid >> 6, lane = tid & 63;
    int g4 = lane >> 4, c16 = lane & 15;
    // XCD-locality decode: consecutive block ids round-robin across 8 XCDs;
    // make bh&7 == id&7 so one XCD sees only heads {x, x+8}.
    int id = blockIdx.x;
    int bh = (id & 7) | ((id >> 3 & 1) << 3);
    int rest = id >> 4;            // 0..63
    int qt = rest & 31;
    int sp = rest >> 5;
    if (causal) qt = 31 - qt;
    size_t rowbase = (size_t)(bh >> 3) * 2048;
    int hoff = (bh & 7) * 64;
    const u16* Q = Qp + rowbase * q_stride + hoff;
    const u16* K = Kp + rowbase * kv_stride + hoff;
    const u16* V = Vp + rowbase * kv_stride + hoff;

    int qrow0 = qt * 64 + wave * 16;
    short8 qf0 = *(const short8*)&Q[(size_t)(qrow0 + c16) * q_stride + g4 * 8];
    short8 qf1 = *(const short8*)&Q[(size_t)(qrow0 + c16) * q_stride + g4 * 8 + 32];

    // staging addresses
    int kr = tid >> 2, ks = (tid & 3) * 16;                 // K: row, u16 col offset
    const u16* Kbase = K + (size_t)kr * kv_stride + ks;
    int vk0 = (tid >> 3) * 2, vs = (tid & 7) * 8;           // V: key pair, dh offset
    const u16* Vbase = V + (size_t)vk0 * kv_stride + vs;

    int4 kv0, kv1, vv0, vv1;
    auto load_tile = [&](int kt) {
        const u16* kp = Kbase + (size_t)kt * 64 * kv_stride;
        kv0 = *(const int4*)(kp);
        kv1 = *(const int4*)(kp + 8);
        const u16* vp = Vbase + (size_t)kt * 64 * kv_stride;
        vv0 = *(const int4*)(vp);
        vv1 = *(const int4*)(vp + kv_stride);
    };
    auto store_tile = [&]() {
        *(int4*)&lK[kr * 72 + ks] = kv0;
        *(int4*)&lK[kr * 72 + ks + 8] = kv1;
        const u16* pa = (const u16*)&vv0;
        const u16* pb = (const u16*)&vv1;
#pragma unroll
        for (int j = 0; j < 8; j++) {
            int dh = vs + j;
            int keyS = vk0 ^ (((dh >> 3) & 3) << 4);       // XOR swizzle kills 8-way bank conflict
            u32 w = (u32)pa[j] | ((u32)pb[j] << 16);
            *(u32*)&lVT[dh * 72 + keyS] = w;
        }
    };

    floatx4 o_acc[4];
#pragma unroll
    for (int d = 0; d < 4; d++) o_acc[d] = (floatx4){0.f, 0.f, 0.f, 0.f};
    float lsum = 0.f;                                       // row sum for qrow = c16
    u16* lPw = lP + wave * 1152;

    int ktend = causal ? (qt + 1) : 32;
    int kt = sp;
    if (kt < ktend) load_tile(kt);

    for (; kt < ktend; kt += 2) {
        __syncthreads();           // prior tile's LDS reads complete
        store_tile();
        __syncthreads();           // staging visible
        if (kt + 2 < ktend) load_tile(kt + 2);   // prefetch overlaps compute

        // S^T = K Q^T : lane holds qrow=c16, keys nt*16 + 4*g4 + r (key-contiguous)
        floatx4 sc[4];
#pragma unroll
        for (int nt = 0; nt < 4; nt++) {
            short8 b0 = *(const short8*)&lK[(nt * 16 + c16) * 72 + g4 * 8];
            short8 b1 = *(const short8*)&lK[(nt * 16 + c16) * 72 + g4 * 8 + 32];
            floatx4 z = (floatx4){0.f, 0.f, 0.f, 0.f};
            z = __builtin_amdgcn_mfma_f32_16x16x32_bf16(b0, qf0, z, 0, 0, 0);
            z = __builtin_amdgcn_mfma_f32_16x16x32_bf16(b1, qf1, z, 0, 0, 0);
            sc[nt] = z;
        }
        if (causal && kt == qt) {
            int qr = qt * 64 + wave * 16 + c16;
#pragma unroll
            for (int nt = 0; nt < 4; nt++) {
                int key0 = kt * 64 + nt * 16 + 4 * g4;
#pragma unroll
                for (int r = 0; r < 4; r++)
                    if (key0 + r > qr) sc[nt][r] = -1e30f;
            }
        }
        // P = exp2(S); per-lane row sum; b64 writes to per-wave lP (no barrier)
#pragma unroll
        for (int nt = 0; nt < 4; nt++) {
            float p0 = exp2f(sc[nt][0]);
            float p1 = exp2f(sc[nt][1]);
            float p2 = exp2f(sc[nt][2]);
            float p3 = exp2f(sc[nt][3]);
            lsum += (p0 + p1) + (p2 + p3);
            __hip_bfloat162 w0 = __float22bfloat162_rn(make_float2(p0, p1));
            __hip_bfloat162 w1 = __float22bfloat162_rn(make_float2(p2, p3));
            uint2 pk; pk.x = *(u32*)&w0; pk.y = *(u32*)&w1;
            *(uint2*)&lPw[c16 * 72 + nt * 16 + 4 * g4] = pk;
        }
        // O += P V
        short8 pa0 = *(const short8*)&lPw[c16 * 72 + g4 * 8];
        short8 pa1 = *(const short8*)&lPw[c16 * 72 + g4 * 8 + 32];
#pragma unroll
        for (int d = 0; d < 4; d++) {
            int swz = ((2 * d + (c16 >> 3)) & 3) << 4;
            short8 vb0 = *(const short8*)&lVT[(d * 16 + c16) * 72 + ((g4 * 8) ^ swz)];
            short8 vb1 = *(const short8*)&lVT[(d * 16 + c16) * 72 + ((32 + g4 * 8) ^ swz)];
            o_acc[d] = __builtin_amdgcn_mfma_f32_16x16x32_bf16(pa0, vb0, o_acc[d], 0, 0, 0);
            o_acc[d] = __builtin_amdgcn_mfma_f32_16x16x32_bf16(pa1, vb1, o_acc[d], 0, 0, 0);
        }
    }

    // reduce lsum across the 4 lanes sharing qrow=c16; store partial sum + unnormalized bf16 O
    lsum += __shfl_xor(lsum, 16);
    lsum += __shfl_xor(lsum, 32);
    size_t slab = (size_t)(sp * 16 + bh) * 2048;
    if (g4 == 0) Lpart[slab + qrow0 + c16] = lsum;
    u16* Ob = Opart + (slab + qrow0) * 64;
#pragma unroll
    for (int d = 0; d < 4; d++)
#pragma unroll
        for (int r = 0; r < 4; r++)
            Ob[(size_t)(4 * g4 + r) * 64 + d * 16 + c16] = f2b(o_acc[d][r]);
}

// ---------------- combine 2 bf16 split partials -> bf16 [4096][512] ----------------
__global__ __launch_bounds__(256) void attn_combine(
    const ushort4* __restrict__ Op,  // [2][16][2048][16 ushort4]
    const float* __restrict__ Lp,    // [2][16][2048]
    ushort4* __restrict__ out)       // [4096][128 ushort4]
{
    int e = blockIdx.x * 256 + threadIdx.x;        // 0 .. 524287
    int dh4 = e & 15;
    int qrow = (e >> 4) & 2047;
    int bh = e >> 15;
    int li = bh * 2048 + qrow;
    float l = Lp[li] + Lp[32768 + li];
    float inv = 1.f / l;
    ushort4 a = Op[e];
    ushort4 b = Op[524288 + e];
    ushort4 o;
    o.x = f2b((b2f(a.x) + b2f(b.x)) * inv);
    o.y = f2b((b2f(a.y) + b2f(b.y)) * inv);
    o.z = f2b((b2f(a.z) + b2f(b.z)) * inv);
    o.w = f2b((b2f(a.w) + b2f(b.w)) * inv);
    int row = (bh >> 3) * 2048 + qrow;
    out[(size_t)row * 128 + (bh & 7) * 16 + dh4] = o;
}

// ---------------- LayerNorm (row=512), in = bf16 slab0 + slab1, emits fp32 and/or bf16 ------
__global__ __launch_bounds__(256) void ln_kernel(const u16* __restrict__ in0,
                                                 const u16* __restrict__ in1,
                                                 const float* __restrict__ g,
                                                 const float* __restrict__ b,
                                                 float* __restrict__ out_f,
                                                 u16* __restrict__ out_b)
{
    const int D = 512;
    int row = blockIdx.x, tid = threadIdx.x;
    size_t base = (size_t)row * D;
    float v0 = b2f(in0[base + tid]) + b2f(in1[base + tid]);
    float v1 = b2f(in0[base + tid + 256]) + b2f(in1[base + tid + 256]);
    float s = v0 + v1, ss = v0 * v0 + v1 * v1;
#pragma unroll
    for (int off = 1; off < 64; off <<= 1) { s += __shfl_xor(s, off); ss += __shfl_xor(ss, off); }
    __shared__ float red[8];
    int wave = tid >> 6, lane = tid & 63;
    if (lane == 0) { red[wave] = s; red[4 + wave] = ss; }
    __syncthreads();
    float st = red[0] + red[1] + red[2] + red[3];
    float sst = red[4] + red[5] + red[6] + red[7];
    float mu = st * (1.f / 512.f);
    float var = sst * (1.f / 512.f) - mu * mu;
    float rs = rsqrtf(var + 1e-5f);
    float y0 = (v0 - mu) * rs * g[tid] + b[tid];
    float y1 = (v1 - mu) * rs * g[tid + 256] + b[tid + 256];
    if (out_f) { out_f[base + tid] = y0; out_f[base + tid + 256] = y1; }
    if (out_b) { out_b[base + tid] = f2b(y0); out_b[base + tid + 256] = f2b(y1); }
}

// ---------------- launch ----------------
extern "C" void kernel_launch(void* const* d_in, const int* in_sizes, int n_in,
                              void* d_out, int out_size, void* d_ws, size_t ws_size,
                              hipStream_t stream)
{
    (void)in_sizes; (void)n_in; (void)out_size; (void)ws_size;
    const float* x     = (const float*)d_in[0];
    const float* enc   = (const float*)d_in[1];
    const float* m_wq  = (const float*)d_in[2];  const float* m_bq = (const float*)d_in[3];
    const float* m_wk  = (const float*)d_in[4];  const float* m_bk = (const float*)d_in[5];
    const float* m_wv  = (const float*)d_in[6];  const float* m_bv = (const float*)d_in[7];
    const float* m_wo  = (const float*)d_in[8];  const float* m_bo = (const float*)d_in[9];
    const float* c_wq  = (const float*)d_in[10]; const float* c_bq = (const float*)d_in[11];
    const float* c_wk  = (const float*)d_in[12]; const float* c_bk = (const float*)d_in[13];
    const float* c_wv  = (const float*)d_in[14]; const float* c_bv = (const float*)d_in[15];
    const float* c_wo  = (const float*)d_in[16]; const float* c_bo = (const float*)d_in[17];
    const float* ln1_g = (const float*)d_in[18]; const float* ln1_b = (const float*)d_in[19];
    const float* ln2_g = (const float*)d_in[20]; const float* ln2_b = (const float*)d_in[21];
    const float* ln3_g = (const float*)d_in[22]; const float* ln3_b = (const float*)d_in[23];
    const float* ff_w1 = (const float*)d_in[24]; const float* ff_b1 = (const float*)d_in[25];
    const float* ff_w2 = (const float*)d_in[26]; const float* ff_b2 = (const float*)d_in[27];

    char* base = (char*)d_ws; size_t off = 0;
    auto alloc = [&](size_t bytes) -> void* {
        void* p = base + off; off = (off + bytes + 255) & ~(size_t)255; return p;
    };
    u16*   Wqkv_m = (u16*)alloc(1536 * 512 * 2);
    u16*   Wo_m   = (u16*)alloc(512 * 512 * 2);
    u16*   Wq_c   = (u16*)alloc(512 * 512 * 2);
    u16*   Wkv_c  = (u16*)alloc(1024 * 512 * 2);
    u16*   Wo_c   = (u16*)alloc(512 * 512 * 2);
    u16*   W1t    = (u16*)alloc(2048 * 512 * 2);
    u16*   W2t    = (u16*)alloc(512 * 2048 * 2);
    float* bqkv_m = (float*)alloc(1536 * 4);
    float* bkv_c  = (float*)alloc(1024 * 4);
    u16*   xb     = (u16*)alloc((size_t)4096 * 512 * 2);
    u16*   encb   = (u16*)alloc((size_t)4096 * 512 * 2);
    u16*   qkvm   = (u16*)alloc((size_t)4096 * 1536 * 2);
    u16*   attnm  = (u16*)alloc((size_t)4096 * 512 * 2);
    u16*   y01    = (u16*)alloc((size_t)2 * 4096 * 512 * 2);   // K-split bf16 partials
    u16*   x1b    = (u16*)alloc((size_t)4096 * 512 * 2);
    u16*   qc     = (u16*)alloc((size_t)4096 * 512 * 2);
    u16*   kvc    = (u16*)alloc((size_t)4096 * 1024 * 2);
    u16*   attnc  = (u16*)alloc((size_t)4096 * 512 * 2);
    u16*   x2b    = (u16*)alloc((size_t)4096 * 512 * 2);
    u16*   h      = (u16*)alloc((size_t)4096 * 2048 * 2);
    u16*   Opart  = (u16*)alloc((size_t)2 * 16 * 2048 * 64 * 2);
    float* Lpart  = (float*)alloc((size_t)2 * 16 * 2048 * 4);

    // ---- preprocessing: 3 launches ----
    TP16 tp;
    tp.e[0] = {m_wq, Wqkv_m,              512, 512};
    tp.e[1] = {m_wk, Wqkv_m + 512 * 512,  512, 512};
    tp.e[2] = {m_wv, Wqkv_m + 1024 * 512, 512, 512};
    tp.e[3] = {m_wo, Wo_m,                512, 512};
    tp.e[4] = {c_wq, Wq_c,                512, 512};
    tp.e[5] = {c_wk, Wkv_c,               512, 512};
    tp.e[6] = {c_wv, Wkv_c + 512 * 512,   512, 512};
    tp.e[7] = {c_wo, Wo_c,                512, 512};
    for (int k = 0; k < 4; k++)
        tp.e[8 + k]  = {ff_w1 + 512 * k,        W1t + k * 512 * 512, 2048, 512};
    for (int k = 0; k < 4; k++)
        tp.e[12 + k] = {ff_w2 + (size_t)512 * k * 512, W2t + 512 * k, 512, 2048};
    transpose_convert16<<<dim3(16, 16, 16), dim3(32, 8), 0, stream>>>(tp);
    gather_bias<<<10, 256, 0, stream>>>(m_bq, m_bk, m_bv, c_bk, c_bv, bqkv_m, bkv_c);
    cvt_bf16_2<<<2048, 256, 0, stream>>>((const float4*)x, (ushort4*)xb,
                                         (const float4*)enc, (ushort4*)encb);

    // ---- fused QKV_m + KV_c projections (KV_c has no upstream deps) ----
    gemm64x128_dual<<<dim3(64, 20), 256, 0, stream>>>(
        xb, Wqkv_m, bqkv_m, qkvm, 1536, 512,
        encb, Wkv_c, bkv_c, kvc, 1024,
        12, 512, 512, 512);

    // ---- self attention block ----
    attn_fused<<<1024, 256, 0, stream>>>(qkvm, 1536, qkvm + 512, 1536, qkvm + 1024,
                                         Opart, Lpart, 1);
    attn_combine<<<2048, 256, 0, stream>>>((const ushort4*)Opart, Lpart, (ushort4*)attnm);
    gemm64x64s<<<dim3(64, 8, 2), 256, 0, stream>>>(attnm, 512, Wo_m, 512, 256,
                                                   m_bo, x, nullptr, y01, 512);
    ln_kernel<<<4096, 256, 0, stream>>>(y01, y01 + (size_t)4096 * 512, ln1_g, ln1_b,
                                        nullptr, x1b);

    // ---- cross attention block ----
    gemm64x64<<<dim3(64, 8), 256, 0, stream>>>(x1b, 512, Wq_c, 512, 512,
                                               c_bq, qc, 512, 512);
    attn_fused<<<1024, 256, 0, stream>>>(qc, 512, kvc, 1024, kvc + 512,
                                         Opart, Lpart, 0);
    attn_combine<<<2048, 256, 0, stream>>>((const ushort4*)Opart, Lpart, (ushort4*)attnc);
    gemm64x64s<<<dim3(64, 8, 2), 256, 0, stream>>>(attnc, 512, Wo_c, 512, 256,
                                                   c_bo, nullptr, x1b, y01, 512);
    ln_kernel<<<4096, 256, 0, stream>>>(y01, y01 + (size_t)4096 * 512, ln2_g, ln2_b,
                                        nullptr, x2b);

    // ---- feed forward ----
    gemm64x128<<<dim3(64, 16), 256, 0, stream>>>(x2b, 512, W1t, 512, 512,
                                                 ff_b1, nullptr, nullptr, h, 2048, 0, 1);
    gemm64x64s<<<dim3(64, 8, 2), 256, 0, stream>>>(h, 2048, W2t, 2048, 1024,
                                                   ff_b2, nullptr, x2b, y01, 512);
    ln_kernel<<<4096, 256, 0, stream>>>(y01, y01 + (size_t)4096 * 512, ln3_g, ln3_b,
                                        (float*)d_out, nullptr);
}

// Round 11
// 315.390 us; speedup vs baseline: 1.2588x; 1.0174x over previous
//
#include <hip/hip_runtime.h>
#include <hip/hip_bf16.h>

typedef __attribute__((ext_vector_type(8))) short short8;
typedef __attribute__((ext_vector_type(4))) float floatx4;
typedef unsigned short u16;
typedef unsigned int u32;

#define QSCALE 0.1803368801111244f   // 0.125 * log2(e): folded into Q so softmax is exp2(S)

__device__ __forceinline__ u16 f2b(float f) {
    union { float f; u32 u; } v; v.f = f;
    u32 r = v.u + 0x7fffu + ((v.u >> 16) & 1u);   // RNE
    return (u16)(r >> 16);
}

__device__ __forceinline__ float b2f(u16 b) {
    u32 u = ((u32)b) << 16;
    union { u32 u; float f; } v; v.u = u;
    return v.f;
}

__device__ __forceinline__ u32 pk2(float a, float b) {
    __hip_bfloat162 w = __float22bfloat162_rn(make_float2(a, b));
    return *(u32*)&w;
}

__device__ __forceinline__ void gload(const u16* g, u16* l) {
    __builtin_amdgcn_global_load_lds((const __attribute__((address_space(1))) void*)g,
                                     (__attribute__((address_space(3))) void*)l, 16, 0, 0);
}

// ---------------- batched weight transpose + fp32->bf16 (16 x 512x512 tiles) ----------------
struct TPent { const float* s; u16* d; int O; int dI; };
struct TP16 { TPent e[16]; };
__global__ __launch_bounds__(256) void transpose_convert16(TP16 p) {
    __shared__ float t[32][33];
    TPent e = p.e[blockIdx.z];
    int o0 = blockIdx.x * 32, i0 = blockIdx.y * 32;
    int tx = threadIdx.x, ty = threadIdx.y;
#pragma unroll
    for (int k = 0; k < 32; k += 8) t[ty + k][tx] = e.s[(size_t)(i0 + ty + k) * e.O + o0 + tx];
    __syncthreads();
#pragma unroll
    for (int k = 0; k < 32; k += 8) e.d[(size_t)(o0 + ty + k) * e.dI + i0 + tx] = f2b(t[tx][ty + k]);
}

// gather 5 bias vectors into 2 concat buffers. grid 10 x 256
__global__ __launch_bounds__(256) void gather_bias(const float* b0, const float* b1, const float* b2,
                                                   const float* b3, const float* b4,
                                                   float* dqkv, float* dkv) {
    int i = blockIdx.x * 256 + threadIdx.x;
    if      (i < 512)  dqkv[i] = b0[i];
    else if (i < 1024) dqkv[i] = b1[i - 512];
    else if (i < 1536) dqkv[i] = b2[i - 1024];
    else if (i < 2048) dkv[i - 1536] = b3[i - 1536];
    else               dkv[i - 1536] = b4[i - 2048];
}

// fp32 -> bf16 for x and enc in one launch. grid 2048 x 256, 4 elems each.
__global__ __launch_bounds__(256) void cvt_bf16_2(const float4* __restrict__ s0, ushort4* __restrict__ d0,
                                                  const float4* __restrict__ s1, ushort4* __restrict__ d1) {
    int i = blockIdx.x * 256 + threadIdx.x;
    float4 v = s0[i];
    ushort4 o; o.x = f2b(v.x); o.y = f2b(v.y); o.z = f2b(v.z); o.w = f2b(v.w);
    d0[i] = o;
    v = s1[i];
    o.x = f2b(v.x); o.y = f2b(v.y); o.z = f2b(v.z); o.w = f2b(v.w);
    d1[i] = o;
}

// ---------------- GEMM 64x128: C = A[M,K] @ Bt[N,K] + epilogue. grid (M/64, N/128) ----------------
__global__ __launch_bounds__(256) void gemm64x128(
    const u16* __restrict__ A, int lda,
    const u16* __restrict__ B, int ldb,
    int K,
    const float* __restrict__ bias,
    const float* __restrict__ residual,
    float* __restrict__ out_f, u16* __restrict__ out_b,
    int out_stride, int scale_ncols, int gelu_flag)
{
    __shared__ u16 lA[64 * 32];
    __shared__ u16 lB[128 * 32];
    int tid = threadIdx.x, wave = tid >> 6, lane = tid & 63;
    int g4 = lane >> 4, c16 = lane & 15;
    int bm = blockIdx.x * 64, bn = blockIdx.y * 128;
    int wm = (wave >> 1) * 32, wn = (wave & 1) * 64;
    int srow = tid >> 2, skseg = (tid & 3) * 8;
    const u16* Ar = A + (size_t)(bm + srow) * lda + skseg;
    const u16* Br = B + (size_t)(bn + srow) * ldb + skseg;
    size_t b64o = (size_t)64 * ldb;

    floatx4 acc[2][4];
#pragma unroll
    for (int i = 0; i < 2; i++)
#pragma unroll
        for (int j = 0; j < 4; j++) acc[i][j] = (floatx4){0.f, 0.f, 0.f, 0.f};

    for (int kt = 0; kt < K; kt += 32) {
        __syncthreads();
        gload(Ar + kt,        lA + wave * 512);
        gload(Br + kt,        lB + wave * 512);
        gload(Br + kt + b64o, lB + 2048 + wave * 512);
        __syncthreads();
        short8 aF[2], bF[4];
#pragma unroll
        for (int i = 0; i < 2; i++) aF[i] = *(const short8*)&lA[(wm + i * 16 + c16) * 32 + g4 * 8];
#pragma unroll
        for (int j = 0; j < 4; j++) bF[j] = *(const short8*)&lB[(wn + j * 16 + c16) * 32 + g4 * 8];
#pragma unroll
        for (int i = 0; i < 2; i++)
#pragma unroll
            for (int j = 0; j < 4; j++)
                acc[i][j] = __builtin_amdgcn_mfma_f32_16x16x32_bf16(aF[i], bF[j], acc[i][j], 0, 0, 0);
    }

#pragma unroll
    for (int i = 0; i < 2; i++) {
        int row0 = bm + wm + i * 16 + g4 * 4;
#pragma unroll
        for (int j = 0; j < 4; j++) {
            int col = bn + wn + j * 16 + c16;
            float bv = bias[col];
#pragma unroll
            for (int r = 0; r < 4; r++) {
                int row = row0 + r;
                float v = acc[i][j][r] + bv;
                if (col < scale_ncols) v *= QSCALE;
                if (gelu_flag) v = 0.5f * v * (1.f + erff(v * 0.70710678118654752f));
                if (residual) v += residual[(size_t)row * out_stride + col];
                if (out_f) out_f[(size_t)row * out_stride + col] = v;
                else       out_b[(size_t)row * out_stride + col] = f2b(v);
            }
        }
    }
}

// ---------------- dual GEMM 64x128 (QKV_m for by<ys, KV_c for by>=ys), bf16 out ----------------
__global__ __launch_bounds__(256) void gemm64x128_dual(
    const u16* __restrict__ A0, const u16* __restrict__ B0, const float* __restrict__ bias0,
    u16* __restrict__ out0, int ostride0, int scale0,
    const u16* __restrict__ A1, const u16* __restrict__ B1, const float* __restrict__ bias1,
    u16* __restrict__ out1, int ostride1,
    int ys, int K, int lda, int ldb)
{
    __shared__ u16 lA[64 * 32];
    __shared__ u16 lB[128 * 32];
    int tid = threadIdx.x, wave = tid >> 6, lane = tid & 63;
    int g4 = lane >> 4, c16 = lane & 15;
    int by = blockIdx.y;
    const u16* A; const u16* B; const float* bias; u16* out; int ostride, scaleN, bn;
    if (by < ys) { A = A0; B = B0; bias = bias0; out = out0; ostride = ostride0; scaleN = scale0; bn = by * 128; }
    else         { A = A1; B = B1; bias = bias1; out = out1; ostride = ostride1; scaleN = 0;      bn = (by - ys) * 128; }
    int bm = blockIdx.x * 64;
    int wm = (wave >> 1) * 32, wn = (wave & 1) * 64;
    int srow = tid >> 2, skseg = (tid & 3) * 8;
    const u16* Ar = A + (size_t)(bm + srow) * lda + skseg;
    const u16* Br = B + (size_t)(bn + srow) * ldb + skseg;
    size_t b64o = (size_t)64 * ldb;

    floatx4 acc[2][4];
#pragma unroll
    for (int i = 0; i < 2; i++)
#pragma unroll
        for (int j = 0; j < 4; j++) acc[i][j] = (floatx4){0.f, 0.f, 0.f, 0.f};

    for (int kt = 0; kt < K; kt += 32) {
        __syncthreads();
        gload(Ar + kt,        lA + wave * 512);
        gload(Br + kt,        lB + wave * 512);
        gload(Br + kt + b64o, lB + 2048 + wave * 512);
        __syncthreads();
        short8 aF[2], bF[4];
#pragma unroll
        for (int i = 0; i < 2; i++) aF[i] = *(const short8*)&lA[(wm + i * 16 + c16) * 32 + g4 * 8];
#pragma unroll
        for (int j = 0; j < 4; j++) bF[j] = *(const short8*)&lB[(wn + j * 16 + c16) * 32 + g4 * 8];
#pragma unroll
        for (int i = 0; i < 2; i++)
#pragma unroll
            for (int j = 0; j < 4; j++)
                acc[i][j] = __builtin_amdgcn_mfma_f32_16x16x32_bf16(aF[i], bF[j], acc[i][j], 0, 0, 0);
    }

#pragma unroll
    for (int i = 0; i < 2; i++) {
        int row0 = bm + wm + i * 16 + g4 * 4;
#pragma unroll
        for (int j = 0; j < 4; j++) {
            int col = bn + wn + j * 16 + c16;
            float bv = bias[col];
#pragma unroll
            for (int r = 0; r < 4; r++) {
                float v = acc[i][j][r] + bv;
                if (col < scaleN) v *= QSCALE;
                out[(size_t)(row0 + r) * ostride + col] = f2b(v);
            }
        }
    }
}

// ---------------- GEMM 64x64, bf16 out, single-pass (used for Q_c) ----------------
__global__ __launch_bounds__(256) void gemm64x64(
    const u16* __restrict__ A, int lda,
    const u16* __restrict__ B, int ldb,
    int K,
    const float* __restrict__ bias,
    u16* __restrict__ out_b,
    int out_stride, int scale_ncols)
{
    __shared__ u16 lA[64 * 32];
    __shared__ u16 lB[64 * 32];
    int tid = threadIdx.x, wave = tid >> 6, lane = tid & 63;
    int g4 = lane >> 4, c16 = lane & 15;
    int bm = blockIdx.x * 64, bn = blockIdx.y * 64;
    int wm = wave * 16;
    int srow = tid >> 2, skseg = (tid & 3) * 8;
    const u16* Ar = A + (size_t)(bm + srow) * lda + skseg;
    const u16* Br = B + (size_t)(bn + srow) * ldb + skseg;

    floatx4 acc[4];
#pragma unroll
    for (int j = 0; j < 4; j++) acc[j] = (floatx4){0.f, 0.f, 0.f, 0.f};

    for (int kt = 0; kt < K; kt += 32) {
        __syncthreads();
        gload(Ar + kt, lA + wave * 512);
        gload(Br + kt, lB + wave * 512);
        __syncthreads();
        short8 aF = *(const short8*)&lA[(wm + c16) * 32 + g4 * 8];
        short8 bF[4];
#pragma unroll
        for (int j = 0; j < 4; j++) bF[j] = *(const short8*)&lB[(j * 16 + c16) * 32 + g4 * 8];
#pragma unroll
        for (int j = 0; j < 4; j++)
            acc[j] = __builtin_amdgcn_mfma_f32_16x16x32_bf16(aF, bF[j], acc[j], 0, 0, 0);
    }

    int row0 = bm + wm + g4 * 4;
#pragma unroll
    for (int j = 0; j < 4; j++) {
        int col = bn + j * 16 + c16;
        float bv = bias[col];
#pragma unroll
        for (int r = 0; r < 4; r++) {
            int row = row0 + r;
            float v = acc[j][r] + bv;
            if (col < scale_ncols) v *= QSCALE;
            out_b[(size_t)row * out_stride + col] = f2b(v);
        }
    }
}

// ---------------- GEMM 64x64 K-split-2: bf16 partials. grid (M/64, N/64, 2) ----------------
// sp==0 adds bias + residual (fp32 OR bf16 source). Consumer (LN) adds the two bf16 slabs.
__global__ __launch_bounds__(256) void gemm64x64s(
    const u16* __restrict__ A, int lda,
    const u16* __restrict__ B, int ldb,
    int Ksub,
    const float* __restrict__ bias,
    const float* __restrict__ res_f,
    const u16* __restrict__ res_b,
    u16* __restrict__ out0, int out_stride)
{
    __shared__ u16 lA[64 * 32];
    __shared__ u16 lB[64 * 32];
    int tid = threadIdx.x, wave = tid >> 6, lane = tid & 63;
    int g4 = lane >> 4, c16 = lane & 15;
    int bm = blockIdx.x * 64, bn = blockIdx.y * 64, sp = blockIdx.z;
    int wm = wave * 16;
    int srow = tid >> 2, skseg = (tid & 3) * 8 + sp * Ksub;
    const u16* Ar = A + (size_t)(bm + srow) * lda + skseg;
    const u16* Br = B + (size_t)(bn + srow) * ldb + skseg;

    floatx4 acc[4];
#pragma unroll
    for (int j = 0; j < 4; j++) acc[j] = (floatx4){0.f, 0.f, 0.f, 0.f};

    for (int kt = 0; kt < Ksub; kt += 32) {
        __syncthreads();
        gload(Ar + kt, lA + wave * 512);
        gload(Br + kt, lB + wave * 512);
        __syncthreads();
        short8 aF = *(const short8*)&lA[(wm + c16) * 32 + g4 * 8];
        short8 bF[4];
#pragma unroll
        for (int j = 0; j < 4; j++) bF[j] = *(const short8*)&lB[(j * 16 + c16) * 32 + g4 * 8];
#pragma unroll
        for (int j = 0; j < 4; j++)
            acc[j] = __builtin_amdgcn_mfma_f32_16x16x32_bf16(aF, bF[j], acc[j], 0, 0, 0);
    }

    u16* out = out0 + (size_t)sp * 4096 * 512;
    int row0 = bm + wm + g4 * 4;
#pragma unroll
    for (int j = 0; j < 4; j++) {
        int col = bn + j * 16 + c16;
        float bv = (sp == 0) ? bias[col] : 0.f;
#pragma unroll
        for (int r = 0; r < 4; r++) {
            int row = row0 + r;
            float v = acc[j][r] + bv;
            if (sp == 0) {
                if (res_f)      v += res_f[(size_t)row * out_stride + col];
                else if (res_b) v += b2f(res_b[(size_t)row * out_stride + col]);
            }
            out[(size_t)row * out_stride + col] = f2b(v);
        }
    }
}

// ---------------- flash attention v7: permuted-K staging eliminates lP (18.4 KB LDS) -------
// grid 1024 (flattened, XCD-swizzled), block 256. 64-row Q-tile, 2-way key split.
// K rows staged in permuted order row(k) = 16*(2*(k>>5)+((k>>2)&1)) + 4*((k>>3)&3) + (k&3):
// S^T then lands so PV A-frags are a pure register repack (no LDS round-trip).
// bf16 unnormalized O partials + fp32 row sums.
__global__ __launch_bounds__(256) void attn_fused(
    const u16* __restrict__ Qp, int q_stride,
    const u16* __restrict__ Kp, int kv_stride,
    const u16* __restrict__ Vp,
    u16* __restrict__ Opart,     // [2][16][2048][64] bf16
    float* __restrict__ Lpart,   // [2][16][2048]
    int causal)
{
    __shared__ u16 lK[64 * 72];    // [permuted key row][dh]
    __shared__ u16 lVT[64 * 72];   // [dh][key^swz], natural key order
    int tid = threadIdx.x, wave = tid >> 6, lane = tid & 63;
    int g4 = lane >> 4, c16 = lane & 15;
    // XCD-locality decode: bh&7 == id&7 so one XCD sees only heads {x, x+8}.
    int id = blockIdx.x;
    int bh = (id & 7) | ((id >> 3 & 1) << 3);
    int rest = id >> 4;            // 0..63
    int qt = rest & 31;
    int sp = rest >> 5;
    if (causal) qt = 31 - qt;
    size_t rowbase = (size_t)(bh >> 3) * 2048;
    int hoff = (bh & 7) * 64;
    const u16* Q = Qp + rowbase * q_stride + hoff;
    const u16* K = Kp + rowbase * kv_stride + hoff;
    const u16* V = Vp + rowbase * kv_stride + hoff;

    int qrow0 = qt * 64 + wave * 16;
    short8 qf0 = *(const short8*)&Q[(size_t)(qrow0 + c16) * q_stride + g4 * 8];
    short8 qf1 = *(const short8*)&Q[(size_t)(qrow0 + c16) * q_stride + g4 * 8 + 32];

    // staging addresses
    int kr = tid >> 2, ks = (tid & 3) * 16;                 // K: key, u16 col offset
    // permuted destination row for key kr
    int krow = 16 * (2 * (kr >> 5) + ((kr >> 2) & 1)) + 4 * ((kr >> 3) & 3) + (kr & 3);
    const u16* Kbase = K + (size_t)kr * kv_stride + ks;
    int vk0 = (tid >> 3) * 2, vs = (tid & 7) * 8;           // V: key pair, dh offset
    const u16* Vbase = V + (size_t)vk0 * kv_stride + vs;

    int4 kv0, kv1, vv0, vv1;
    auto load_tile = [&](int kt) {
        const u16* kp = Kbase + (size_t)kt * 64 * kv_stride;
        kv0 = *(const int4*)(kp);
        kv1 = *(const int4*)(kp + 8);
        const u16* vp = Vbase + (size_t)kt * 64 * kv_stride;
        vv0 = *(const int4*)(vp);
        vv1 = *(const int4*)(vp + kv_stride);
    };
    auto store_tile = [&]() {
        *(int4*)&lK[krow * 72 + ks] = kv0;
        *(int4*)&lK[krow * 72 + ks + 8] = kv1;
        const u16* pa = (const u16*)&vv0;
        const u16* pb = (const u16*)&vv1;
#pragma unroll
        for (int j = 0; j < 8; j++) {
            int dh = vs + j;
            int keyS = vk0 ^ (((dh >> 3) & 3) << 4);       // XOR swizzle kills 8-way bank conflict
            u32 w = (u32)pa[j] | ((u32)pb[j] << 16);
            *(u32*)&lVT[dh * 72 + keyS] = w;
        }
    };

    floatx4 o_acc[4];
#pragma unroll
    for (int d = 0; d < 4; d++) o_acc[d] = (floatx4){0.f, 0.f, 0.f, 0.f};
    float lsum = 0.f;                                       // row sum for qrow = c16

    int ktend = causal ? (qt + 1) : 32;
    int kt = sp;
    if (kt < ktend) load_tile(kt);

    for (; kt < ktend; kt += 2) {
        __syncthreads();           // prior tile's LDS reads complete
        store_tile();
        __syncthreads();           // staging visible
        if (kt + 2 < ktend) load_tile(kt + 2);   // prefetch overlaps compute

        // S^T = K Q^T over permuted key rows: lane (c16,g4) reg (nt,r) holds score for
        // actual key  8*g4 + 4*(nt&1) + r + 32*(nt>>1).
        floatx4 sc[4];
#pragma unroll
        for (int nt = 0; nt < 4; nt++) {
            short8 b0 = *(const short8*)&lK[(nt * 16 + c16) * 72 + g4 * 8];
            short8 b1 = *(const short8*)&lK[(nt * 16 + c16) * 72 + g4 * 8 + 32];
            floatx4 z = (floatx4){0.f, 0.f, 0.f, 0.f};
            z = __builtin_amdgcn_mfma_f32_16x16x32_bf16(b0, qf0, z, 0, 0, 0);
            z = __builtin_amdgcn_mfma_f32_16x16x32_bf16(b1, qf1, z, 0, 0, 0);
            sc[nt] = z;
        }
        if (causal && kt == qt) {
            int qr = qt * 64 + wave * 16 + c16;
#pragma unroll
            for (int nt = 0; nt < 4; nt++) {
                int key0 = kt * 64 + 8 * g4 + 4 * (nt & 1) + 32 * (nt >> 1);
#pragma unroll
                for (int r = 0; r < 4; r++)
                    if (key0 + r > qr) sc[nt][r] = -1e30f;
            }
        }
        // P = exp2(S); per-lane row sum; pure register repack into A-frags
        float e[4][4];
#pragma unroll
        for (int nt = 0; nt < 4; nt++) {
#pragma unroll
            for (int r = 0; r < 4; r++) {
                e[nt][r] = exp2f(sc[nt][r]);
                lsum += e[nt][r];
            }
        }
        short8 pa0, pa1;
        {
            u32 w[8];
            w[0] = pk2(e[0][0], e[0][1]); w[1] = pk2(e[0][2], e[0][3]);
            w[2] = pk2(e[1][0], e[1][1]); w[3] = pk2(e[1][2], e[1][3]);
            w[4] = pk2(e[2][0], e[2][1]); w[5] = pk2(e[2][2], e[2][3]);
            w[6] = pk2(e[3][0], e[3][1]); w[7] = pk2(e[3][2], e[3][3]);
            pa0 = *(short8*)&w[0];
            pa1 = *(short8*)&w[4];
        }
        // O += P V (V in natural key order; store/read swizzles cancel)
#pragma unroll
        for (int d = 0; d < 4; d++) {
            int swz = ((2 * d + (c16 >> 3)) & 3) << 4;
            short8 vb0 = *(const short8*)&lVT[(d * 16 + c16) * 72 + ((g4 * 8) ^ swz)];
            short8 vb1 = *(const short8*)&lVT[(d * 16 + c16) * 72 + ((32 + g4 * 8) ^ swz)];
            o_acc[d] = __builtin_amdgcn_mfma_f32_16x16x32_bf16(pa0, vb0, o_acc[d], 0, 0, 0);
            o_acc[d] = __builtin_amdgcn_mfma_f32_16x16x32_bf16(pa1, vb1, o_acc[d], 0, 0, 0);
        }
    }

    // reduce lsum across the 4 lanes sharing qrow=c16; store partial sum + unnormalized bf16 O
    lsum += __shfl_xor(lsum, 16);
    lsum += __shfl_xor(lsum, 32);
    size_t slab = (size_t)(sp * 16 + bh) * 2048;
    if (g4 == 0) Lpart[slab + qrow0 + c16] = lsum;
    u16* Ob = Opart + (slab + qrow0) * 64;
#pragma unroll
    for (int d = 0; d < 4; d++)
#pragma unroll
        for (int r = 0; r < 4; r++)
            Ob[(size_t)(4 * g4 + r) * 64 + d * 16 + c16] = f2b(o_acc[d][r]);
}

// ---------------- combine 2 bf16 split partials -> bf16 [4096][512] ----------------
__global__ __launch_bounds__(256) void attn_combine(
    const ushort4* __restrict__ Op,  // [2][16][2048][16 ushort4]
    const float* __restrict__ Lp,    // [2][16][2048]
    ushort4* __restrict__ out)       // [4096][128 ushort4]
{
    int e = blockIdx.x * 256 + threadIdx.x;        // 0 .. 524287
    int dh4 = e & 15;
    int qrow = (e >> 4) & 2047;
    int bh = e >> 15;
    int li = bh * 2048 + qrow;
    float l = Lp[li] + Lp[32768 + li];
    float inv = 1.f / l;
    ushort4 a = Op[e];
    ushort4 b = Op[524288 + e];
    ushort4 o;
    o.x = f2b((b2f(a.x) + b2f(b.x)) * inv);
    o.y = f2b((b2f(a.y) + b2f(b.y)) * inv);
    o.z = f2b((b2f(a.z) + b2f(b.z)) * inv);
    o.w = f2b((b2f(a.w) + b2f(b.w)) * inv);
    int row = (bh >> 3) * 2048 + qrow;
    out[(size_t)row * 128 + (bh & 7) * 16 + dh4] = o;
}

// ---------------- LayerNorm (row=512), in = bf16 slab0 + slab1, emits fp32 and/or bf16 ------
__global__ __launch_bounds__(256) void ln_kernel(const u16* __restrict__ in0,
                                                 const u16* __restrict__ in1,
                                                 const float* __restrict__ g,
                                                 const float* __restrict__ b,
                                                 float* __restrict__ out_f,
                                                 u16* __restrict__ out_b)
{
    const int D = 512;
    int row = blockIdx.x, tid = threadIdx.x;
    size_t base = (size_t)row * D;
    float v0 = b2f(in0[base + tid]) + b2f(in1[base + tid]);
    float v1 = b2f(in0[base + tid + 256]) + b2f(in1[base + tid + 256]);
    float s = v0 + v1, ss = v0 * v0 + v1 * v1;
#pragma unroll
    for (int off = 1; off < 64; off <<= 1) { s += __shfl_xor(s, off); ss += __shfl_xor(ss, off); }
    __shared__ float red[8];
    int wave = tid >> 6, lane = tid & 63;
    if (lane == 0) { red[wave] = s; red[4 + wave] = ss; }
    __syncthreads();
    float st = red[0] + red[1] + red[2] + red[3];
    float sst = red[4] + red[5] + red[6] + red[7];
    float mu = st * (1.f / 512.f);
    float var = sst * (1.f / 512.f) - mu * mu;
    float rs = rsqrtf(var + 1e-5f);
    float y0 = (v0 - mu) * rs * g[tid] + b[tid];
    float y1 = (v1 - mu) * rs * g[tid + 256] + b[tid + 256];
    if (out_f) { out_f[base + tid] = y0; out_f[base + tid + 256] = y1; }
    if (out_b) { out_b[base + tid] = f2b(y0); out_b[base + tid + 256] = f2b(y1); }
}

// ---------------- launch ----------------
extern "C" void kernel_launch(void* const* d_in, const int* in_sizes, int n_in,
                              void* d_out, int out_size, void* d_ws, size_t ws_size,
                              hipStream_t stream)
{
    (void)in_sizes; (void)n_in; (void)out_size; (void)ws_size;
    const float* x     = (const float*)d_in[0];
    const float* enc   = (const float*)d_in[1];
    const float* m_wq  = (const float*)d_in[2];  const float* m_bq = (const float*)d_in[3];
    const float* m_wk  = (const float*)d_in[4];  const float* m_bk = (const float*)d_in[5];
    const float* m_wv  = (const float*)d_in[6];  const float* m_bv = (const float*)d_in[7];
    const float* m_wo  = (const float*)d_in[8];  const float* m_bo = (const float*)d_in[9];
    const float* c_wq  = (const float*)d_in[10]; const float* c_bq = (const float*)d_in[11];
    const float* c_wk  = (const float*)d_in[12]; const float* c_bk = (const float*)d_in[13];
    const float* c_wv  = (const float*)d_in[14]; const float* c_bv = (const float*)d_in[15];
    const float* c_wo  = (const float*)d_in[16]; const float* c_bo = (const float*)d_in[17];
    const float* ln1_g = (const float*)d_in[18]; const float* ln1_b = (const float*)d_in[19];
    const float* ln2_g = (const float*)d_in[20]; const float* ln2_b = (const float*)d_in[21];
    const float* ln3_g = (const float*)d_in[22]; const float* ln3_b = (const float*)d_in[23];
    const float* ff_w1 = (const float*)d_in[24]; const float* ff_b1 = (const float*)d_in[25];
    const float* ff_w2 = (const float*)d_in[26]; const float* ff_b2 = (const float*)d_in[27];

    char* base = (char*)d_ws; size_t off = 0;
    auto alloc = [&](size_t bytes) -> void* {
        void* p = base + off; off = (off + bytes + 255) & ~(size_t)255; return p;
    };
    u16*   Wqkv_m = (u16*)alloc(1536 * 512 * 2);
    u16*   Wo_m   = (u16*)alloc(512 * 512 * 2);
    u16*   Wq_c   = (u16*)alloc(512 * 512 * 2);
    u16*   Wkv_c  = (u16*)alloc(1024 * 512 * 2);
    u16*   Wo_c   = (u16*)alloc(512 * 512 * 2);
    u16*   W1t    = (u16*)alloc(2048 * 512 * 2);
    u16*   W2t    = (u16*)alloc(512 * 2048 * 2);
    float* bqkv_m = (float*)alloc(1536 * 4);
    float* bkv_c  = (float*)alloc(1024 * 4);
    u16*   xb     = (u16*)alloc((size_t)4096 * 512 * 2);
    u16*   encb   = (u16*)alloc((size_t)4096 * 512 * 2);
    u16*   qkvm   = (u16*)alloc((size_t)4096 * 1536 * 2);
    u16*   attnm  = (u16*)alloc((size_t)4096 * 512 * 2);
    u16*   y01    = (u16*)alloc((size_t)2 * 4096 * 512 * 2);   // K-split bf16 partials
    u16*   x1b    = (u16*)alloc((size_t)4096 * 512 * 2);
    u16*   qc     = (u16*)alloc((size_t)4096 * 512 * 2);
    u16*   kvc    = (u16*)alloc((size_t)4096 * 1024 * 2);
    u16*   attnc  = (u16*)alloc((size_t)4096 * 512 * 2);
    u16*   x2b    = (u16*)alloc((size_t)4096 * 512 * 2);
    u16*   h      = (u16*)alloc((size_t)4096 * 2048 * 2);
    u16*   Opart  = (u16*)alloc((size_t)2 * 16 * 2048 * 64 * 2);
    float* Lpart  = (float*)alloc((size_t)2 * 16 * 2048 * 4);

    // ---- preprocessing: 3 launches ----
    TP16 tp;
    tp.e[0] = {m_wq, Wqkv_m,              512, 512};
    tp.e[1] = {m_wk, Wqkv_m + 512 * 512,  512, 512};
    tp.e[2] = {m_wv, Wqkv_m + 1024 * 512, 512, 512};
    tp.e[3] = {m_wo, Wo_m,                512, 512};
    tp.e[4] = {c_wq, Wq_c,                512, 512};
    tp.e[5] = {c_wk, Wkv_c,               512, 512};
    tp.e[6] = {c_wv, Wkv_c + 512 * 512,   512, 512};
    tp.e[7] = {c_wo, Wo_c,                512, 512};
    for (int k = 0; k < 4; k++)
        tp.e[8 + k]  = {ff_w1 + 512 * k,        W1t + k * 512 * 512, 2048, 512};
    for (int k = 0; k < 4; k++)
        tp.e[12 + k] = {ff_w2 + (size_t)512 * k * 512, W2t + 512 * k, 512, 2048};
    transpose_convert16<<<dim3(16, 16, 16), dim3(32, 8), 0, stream>>>(tp);
    gather_bias<<<10, 256, 0, stream>>>(m_bq, m_bk, m_bv, c_bk, c_bv, bqkv_m, bkv_c);
    cvt_bf16_2<<<2048, 256, 0, stream>>>((const float4*)x, (ushort4*)xb,
                                         (const float4*)enc, (ushort4*)encb);

    // ---- fused QKV_m + KV_c projections (KV_c has no upstream deps) ----
    gemm64x128_dual<<<dim3(64, 20), 256, 0, stream>>>(
        xb, Wqkv_m, bqkv_m, qkvm, 1536, 512,
        encb, Wkv_c, bkv_c, kvc, 1024,
        12, 512, 512, 512);

    // ---- self attention block ----
    attn_fused<<<1024, 256, 0, stream>>>(qkvm, 1536, qkvm + 512, 1536, qkvm + 1024,
                                         Opart, Lpart, 1);
    attn_combine<<<2048, 256, 0, stream>>>((const ushort4*)Opart, Lpart, (ushort4*)attnm);
    gemm64x64s<<<dim3(64, 8, 2), 256, 0, stream>>>(attnm, 512, Wo_m, 512, 256,
                                                   m_bo, x, nullptr, y01, 512);
    ln_kernel<<<4096, 256, 0, stream>>>(y01, y01 + (size_t)4096 * 512, ln1_g, ln1_b,
                                        nullptr, x1b);

    // ---- cross attention block ----
    gemm64x64<<<dim3(64, 8), 256, 0, stream>>>(x1b, 512, Wq_c, 512, 512,
                                               c_bq, qc, 512, 512);
    attn_fused<<<1024, 256, 0, stream>>>(qc, 512, kvc, 1024, kvc + 512,
                                         Opart, Lpart, 0);
    attn_combine<<<2048, 256, 0, stream>>>((const ushort4*)Opart, Lpart, (ushort4*)attnc);
    gemm64x64s<<<dim3(64, 8, 2), 256, 0, stream>>>(attnc, 512, Wo_c, 512, 256,
                                                   c_bo, nullptr, x1b, y01, 512);
    ln_kernel<<<4096, 256, 0, stream>>>(y01, y01 + (size_t)4096 * 512, ln2_g, ln2_b,
                                        nullptr, x2b);

    // ---- feed forward ----
    gemm64x128<<<dim3(64, 16), 256, 0, stream>>>(x2b, 512, W1t, 512, 512,
                                                 ff_b1, nullptr, nullptr, h, 2048, 0, 1);
    gemm64x64s<<<dim3(64, 8, 2), 256, 0, stream>>>(h, 2048, W2t, 2048, 1024,
                                                   ff_b2, nullptr, x2b, y01, 512);
    ln_kernel<<<4096, 256, 0, stream>>>(y01, y01 + (size_t)4096 * 512, ln3_g, ln3_b,
                                        (float*)d_out, nullptr);
}